// Round 3
// baseline (2778.966 us; speedup 1.0000x reference)
//
#include <hip/hip_runtime.h>

namespace {

constexpr int N   = 100000;
constexpr int E   = 600000;
constexpr int B   = 50;
constexpr int F   = 40;
constexpr int TF  = B * F;     // 2000
constexpr int D0  = 64;
constexpr int H   = 128;
constexpr int C   = 2;

// ---------------- histograms / CSR build ----------------

__global__ void hist_edges(const int* __restrict__ dst, int* __restrict__ deg) {
  int e = blockIdx.x * 256 + threadIdx.x;
  if (e < E) atomicAdd(&deg[dst[e]], 1);
}

// LDS histogram: avoids L2 same-address atomic serialization (was 575 us with
// direct global atomics: all lanes share one graph id -> 2 cache lines).
__global__ void hist_nodes(const int* __restrict__ b0, const int* __restrict__ a0l,
                           int* __restrict__ cnt1, int* __restrict__ assign0) {
  __shared__ int lh[TF];
  int t = threadIdx.x;
  for (int j = t; j < TF; j += 256) lh[j] = 0;
  __syncthreads();
  int i = blockIdx.x * 256 + t;
  if (i < N) {
    int g = b0[i];
    int a = g * F + a0l[i];
    assign0[i] = a;
    atomicAdd(&lh[a], 1);
  }
  __syncthreads();
  for (int j = t; j < TF; j += 256) {
    int c = lh[j];
    if (c) atomicAdd(&cnt1[j], c);
  }
}

__global__ void scan1(const int* __restrict__ cnt, int* __restrict__ offs,
                      int* __restrict__ part) {
  __shared__ int lds[256];
  int t = threadIdx.x;
  int base = blockIdx.x * 1024 + t * 4;
  int v[4];
#pragma unroll
  for (int j = 0; j < 4; ++j) v[j] = (base + j < N) ? cnt[base + j] : 0;
  int s = v[0] + v[1] + v[2] + v[3];
  lds[t] = s;
  __syncthreads();
  for (int off = 1; off < 256; off <<= 1) {
    int x = (t >= off) ? lds[t - off] : 0;
    __syncthreads();
    lds[t] += x;
    __syncthreads();
  }
  int ex = lds[t] - s;
  if (t == 255) part[blockIdx.x] = lds[255];
  int run = ex;
#pragma unroll
  for (int j = 0; j < 4; ++j) {
    if (base + j < N) offs[base + j] = run;
    run += v[j];
  }
}

__global__ void scan2(const int* __restrict__ part, int* __restrict__ partEx, int nb) {
  __shared__ int lds[128];
  int t = threadIdx.x;
  int s = (t < nb) ? part[t] : 0;
  lds[t] = s;
  __syncthreads();
  for (int off = 1; off < 128; off <<= 1) {
    int x = (t >= off) ? lds[t - off] : 0;
    __syncthreads();
    lds[t] += x;
    __syncthreads();
  }
  partEx[t] = lds[t] - s;
}

__global__ void scan3(int* __restrict__ offs, const int* __restrict__ partEx,
                      const int* __restrict__ deg, float* __restrict__ rdeg,
                      const int* __restrict__ cnt1, float* __restrict__ rdeg1,
                      float* __restrict__ rdegB, int* __restrict__ assign1) {
  int i = blockIdx.x * 256 + threadIdx.x;
  if (i < N) {
    offs[i] += partEx[i >> 10];
    rdeg[i] = 1.0f / fmaxf((float)deg[i], 1.0f);
    if (i == 0) offs[N] = E;
    if (i < TF) { rdeg1[i] = 1.0f / fmaxf((float)cnt1[i], 1.0f); assign1[i] = i / F; }
    if (i < B) {
      int s = 0;
      for (int f = 0; f < F; ++f) s += cnt1[i * F + f];
      rdegB[i] = 1.0f / fmaxf((float)s, 1.0f);
    }
  }
}

__global__ void scatter_k(const int* __restrict__ src, const int* __restrict__ dst,
                          const int* __restrict__ offs, int* __restrict__ cursor,
                          int* __restrict__ srcS) {
  int e = blockIdx.x * 256 + threadIdx.x;
  if (e < E) {
    int d = dst[e];
    int pos = offs[d] + atomicAdd(&cursor[d], 1);
    srcS[pos] = src[e];
  }
}

// ---------------- edge aggregation: mean over incoming src rows ----------------
// one wave per dst node; lane covers 2 columns (float2); 2-way edge unroll to
// break the serial gather-latency chain
__global__ void agg_k(const float* __restrict__ h, const int* __restrict__ offs,
                      const int* __restrict__ srcS, const float* __restrict__ rdeg,
                      float* __restrict__ out) {
  int wid = blockIdx.x * 4 + (threadIdx.x >> 6);
  int lane = threadIdx.x & 63;
  if (wid >= N) return;
  int o0 = offs[wid], o1 = offs[wid + 1];
  float ax = 0.f, ay = 0.f, bx = 0.f, by = 0.f;
  int e = o0;
  for (; e + 1 < o1; e += 2) {
    int s0 = srcS[e], s1 = srcS[e + 1];
    float2 v0 = ((const float2*)(h + (size_t)s0 * H))[lane];
    float2 v1 = ((const float2*)(h + (size_t)s1 * H))[lane];
    ax += v0.x; ay += v0.y; bx += v1.x; by += v1.y;
  }
  if (e < o1) {
    int s0 = srcS[e];
    float2 v0 = ((const float2*)(h + (size_t)s0 * H))[lane];
    ax += v0.x; ay += v0.y;
  }
  float sc = rdeg[wid];
  float2 r; r.x = (ax + bx) * sc; r.y = (ay + by) * sc;
  ((float2*)(out + (size_t)wid * H))[lane] = r;
}

// ---------------- generic fused fp32 GEMM ----------------
// out[i][:] = (relu?)( A[i,:]@W1 + [Agg[i,:]*(scale?)]@W2 + Gt[Gidx[i],:] + bias )
// tile 128 rows x 128 cols, 256 threads, 8x8 micro-tile, K-chunks of 16.
// Double-buffered LDS + register prefetch: ONE barrier per chunk (reads of
// buf[b^1] finished behind the previous iteration's barrier before we write it).
template <int K, bool AGG, bool GATH, bool RELU, bool SCALE>
__global__ __launch_bounds__(256)
void gemm_k(const float* __restrict__ A, const float* __restrict__ W1,
            const float* __restrict__ Agg, const float* __restrict__ W2,
            const float* __restrict__ ascale,
            const float* __restrict__ Gt, const int* __restrict__ Gidx,
            const float* __restrict__ bias, int hasBias,
            float* __restrict__ out, int n) {
  constexpr int BM = 128, KC = 16;
  constexpr int NCH = (AGG ? 2 : 1) * (K / KC);
  __shared__ float As[2][KC][BM + 4];
  __shared__ float Ws[2][KC][H + 4];
  const int t = threadIdx.x;
  const int tx = t & 15, ty = t >> 4;
  const int row0 = blockIdx.x * BM;
  float acc[8][8];
#pragma unroll
  for (int r = 0; r < 8; ++r)
#pragma unroll
    for (int c = 0; c < 8; ++c) acc[r][c] = 0.f;

  const int sr = t >> 1;        // staging row 0..127
  const int sk = (t & 1) * 8;   // staging k offset 0/8
  const int wk = t >> 4;        // weight k row 0..15
  const int wc = (t & 15) * 8;  // weight col 0..120

  auto loadChunk = [&](int ch, float4& a0, float4& a1, float4& w0, float4& w1) {
    const int pass = AGG ? (ch >= (K / KC) ? 1 : 0) : 0;
    const int k0 = (ch - pass * (K / KC)) * KC;
    const float* Ain = (AGG && pass) ? Agg : A;
    const float* Win = (AGG && pass) ? W2 : W1;
    a0 = make_float4(0, 0, 0, 0); a1 = make_float4(0, 0, 0, 0);
    int r = row0 + sr;
    if (r < n) {
      const float* ap = Ain + (size_t)r * K + k0 + sk;
      a0 = *(const float4*)ap;
      a1 = *(const float4*)(ap + 4);
      if (AGG && SCALE && pass) {
        float sc = ascale[r];
        a0.x *= sc; a0.y *= sc; a0.z *= sc; a0.w *= sc;
        a1.x *= sc; a1.y *= sc; a1.z *= sc; a1.w *= sc;
      }
    }
    const float* wp = Win + (size_t)(k0 + wk) * H + wc;
    w0 = *(const float4*)wp;
    w1 = *(const float4*)(wp + 4);
  };

  auto stageChunk = [&](int buf, const float4& a0, const float4& a1,
                        const float4& w0, const float4& w1) {
    As[buf][sk + 0][sr] = a0.x; As[buf][sk + 1][sr] = a0.y;
    As[buf][sk + 2][sr] = a0.z; As[buf][sk + 3][sr] = a0.w;
    As[buf][sk + 4][sr] = a1.x; As[buf][sk + 5][sr] = a1.y;
    As[buf][sk + 6][sr] = a1.z; As[buf][sk + 7][sr] = a1.w;
    *(float4*)&Ws[buf][wk][wc] = w0;
    *(float4*)&Ws[buf][wk][wc + 4] = w1;
  };

  {
    float4 a0, a1, w0, w1;
    loadChunk(0, a0, a1, w0, w1);
    stageChunk(0, a0, a1, w0, w1);
  }
  __syncthreads();

  for (int c = 0; c < NCH; ++c) {
    const int cb = c & 1;
    float4 a0n, a1n, w0n, w1n;
    const bool more = (c + 1 < NCH);
    if (more) loadChunk(c + 1, a0n, a1n, w0n, w1n);  // global loads in flight
#pragma unroll
    for (int k = 0; k < KC; ++k) {
      float4 av0 = *(const float4*)&As[cb][k][ty * 8];
      float4 av1 = *(const float4*)&As[cb][k][ty * 8 + 4];
      float4 bv0 = *(const float4*)&Ws[cb][k][tx * 8];
      float4 bv1 = *(const float4*)&Ws[cb][k][tx * 8 + 4];
      float a_[8] = {av0.x, av0.y, av0.z, av0.w, av1.x, av1.y, av1.z, av1.w};
      float b_[8] = {bv0.x, bv0.y, bv0.z, bv0.w, bv1.x, bv1.y, bv1.z, bv1.w};
#pragma unroll
      for (int rr = 0; rr < 8; ++rr)
#pragma unroll
        for (int cc = 0; cc < 8; ++cc) acc[rr][cc] += a_[rr] * b_[cc];
    }
    if (more) {
      stageChunk(cb ^ 1, a0n, a1n, w0n, w1n);
      __syncthreads();
    }
  }

#pragma unroll
  for (int rr = 0; rr < 8; ++rr) {
    int row = row0 + ty * 8 + rr;
    if (row >= n) continue;
    const float* grow = nullptr;
    if (GATH) grow = Gt + (size_t)Gidx[row] * H;
    float v[8];
#pragma unroll
    for (int cc = 0; cc < 8; ++cc) {
      int col = tx * 8 + cc;
      float x = acc[rr][cc];
      if (hasBias) x += bias[col];
      if (GATH) x += grow[col];
      if (RELU) x = fmaxf(x, 0.f);
      v[cc] = x;
    }
    float* op = out + (size_t)row * H + tx * 8;
    *(float4*)op = make_float4(v[0], v[1], v[2], v[3]);
    *(float4*)(op + 4) = make_float4(v[4], v[5], v[6], v[7]);
  }
}

// ---------------- pooling ----------------
// node->function sums: 400 blocks (250 rows each), LDS column-partitioned acc
__global__ void pool_p01(const float* __restrict__ h0, const int* __restrict__ a0l,
                         const int* __restrict__ b0, float* __restrict__ p01s) {
  __shared__ float acc[F][H];
  int t = threadIdx.x;  // 128
#pragma unroll
  for (int f = 0; f < F; ++f) acc[f][t] = 0.f;
  int rowbase = blockIdx.x * 250;
  for (int i = 0; i < 250; ++i) {
    int r = rowbase + i;
    acc[a0l[r]][t] += h0[(size_t)r * H + t];
  }
  int g = b0[rowbase];
#pragma unroll
  for (int f = 0; f < F; ++f)
    atomicAdd(&p01s[((size_t)(g * F + f)) * H + t], acc[f][t]);
}

__global__ void pool_g0(const float* __restrict__ h0, const int* __restrict__ b0,
                        float* __restrict__ g0s) {
  int t = threadIdx.x;
  int rowbase = blockIdx.x * 250;
  float a = 0.f;
  for (int i = 0; i < 250; ++i) a += h0[(size_t)(rowbase + i) * H + t];
  atomicAdd(&g0s[(size_t)b0[rowbase] * H + t], a);
}

// mean over F contiguous rows per graph (assign1 = i//F is contiguous)
__global__ void mean40(const float* __restrict__ hin, float* __restrict__ outp) {
  int t = threadIdx.x, g = blockIdx.x;
  float a = 0.f;
  for (int i = 0; i < F; ++i) a += hin[(size_t)(g * F + i) * H + t];
  outp[(size_t)g * H + t] = a * (1.0f / F);
}

// ---------------- head MLP ----------------
__global__ void head_k(const float* __restrict__ g0s, const float* __restrict__ rdegB,
                       const float* __restrict__ g1, const float* __restrict__ h2,
                       const float* __restrict__ W1h, const float* __restrict__ b1h,
                       const float* __restrict__ W2h, const float* __restrict__ b2h,
                       float* __restrict__ out) {
  __shared__ float gv[3 * H];
  __shared__ float z[H];
  int b = blockIdx.x, t = threadIdx.x;
  gv[t] = g0s[(size_t)b * H + t] * rdegB[b];
  gv[H + t] = g1[(size_t)b * H + t];
  gv[2 * H + t] = h2[(size_t)b * H + t];
  __syncthreads();
  float s = b1h[t];
  for (int k = 0; k < 3 * H; ++k) s += gv[k] * W1h[k * H + t];
  z[t] = fmaxf(s, 0.f);
  __syncthreads();
  if (t < C) {
    float o = b2h[t];
    for (int k = 0; k < H; ++k) o += z[k] * W2h[k * C + t];
    out[b * C + t] = o;
  }
}

}  // namespace

extern "C" void kernel_launch(void* const* d_in, const int* in_sizes, int n_in,
                              void* d_out, int out_size, void* d_ws, size_t ws_size,
                              hipStream_t stream) {
  (void)in_sizes; (void)n_in; (void)out_size; (void)ws_size;
  const float* x0   = (const float*)d_in[0];
  const int*   ei   = (const int*)d_in[1];
  const int*   src  = ei;
  const int*   dst  = ei + E;
  const int*   b0   = (const int*)d_in[2];
  const int*   a0l  = (const int*)d_in[3];
  const float* Wp   = (const float*)d_in[4];
  const float* bp   = (const float*)d_in[5];
  const float* e0in_Ws = (const float*)d_in[6];
  const float* e0in_Wn = (const float*)d_in[7];
  const float* e0in_b  = (const float*)d_in[8];
  const float* enc0_Ws = (const float*)d_in[9];
  const float* enc0_Wn = (const float*)d_in[10];
  const float* enc0_b  = (const float*)d_in[11];
  const float* e1in_Ws = (const float*)d_in[12];
  const float* e1in_b  = (const float*)d_in[13];
  const float* e2in_Ws = (const float*)d_in[14];
  const float* e2in_b  = (const float*)d_in[15];
  const float* enc1_Ws = (const float*)d_in[16];
  const float* enc1_b  = (const float*)d_in[17];
  const float* enc2_Ws = (const float*)d_in[18];
  const float* enc2_b  = (const float*)d_in[19];
  const float* A0 = (const float*)d_in[20];
  const float* A1 = (const float*)d_in[21];
  const float* A2 = (const float*)d_in[22];
  const float* U0 = (const float*)d_in[23];
  const float* U1 = (const float*)d_in[24];
  const float* D1 = (const float*)d_in[25];
  const float* D2 = (const float*)d_in[26];
  const float* ib0 = (const float*)d_in[27];
  const float* ib1 = (const float*)d_in[28];
  const float* ib2 = (const float*)d_in[29];
  const float* H1w = (const float*)d_in[30];
  const float* hb1 = (const float*)d_in[31];
  const float* H2w = (const float*)d_in[32];
  const float* hb2 = (const float*)d_in[33];
  float* out = (float*)d_out;

  // ---- workspace carve ----
  char* p = (char*)d_ws;
  auto carve = [&](size_t bytes) {
    char* r = p;
    p += (bytes + 255) & ~(size_t)255;
    return r;
  };
  char* z0 = p;  // zeroed-every-call region
  int*   deg    = (int*)carve((size_t)N * 4);
  int*   cursor = (int*)carve((size_t)N * 4);
  int*   cnt1   = (int*)carve((size_t)TF * 4);
  float* h1a    = (float*)carve((size_t)TF * H * 4);
  float* h2a    = (float*)carve((size_t)B * H * 4);
  float* g0s    = (float*)carve((size_t)B * H * 4);
  size_t zbytes = (size_t)(p - z0);
  float* h0   = (float*)carve((size_t)N * H * 4);
  float* agg  = (float*)carve((size_t)N * H * 4);
  float* h1b  = (float*)carve((size_t)TF * H * 4);
  float* h1d  = (float*)carve((size_t)TF * H * 4);
  float* p01s = (float*)carve((size_t)TF * H * 4);
  float* h2b  = (float*)carve((size_t)B * H * 4);
  float* h2d  = (float*)carve((size_t)B * H * 4);
  float* p12  = (float*)carve((size_t)B * H * 4);
  float* g1   = (float*)carve((size_t)B * H * 4);
  float* rdeg = (float*)carve((size_t)N * 4);
  float* rdeg1 = (float*)carve((size_t)TF * 4);
  float* rdegB = (float*)carve(64 * 4);
  int* offs    = (int*)carve((size_t)(N + 64) * 4);
  int* srcS    = (int*)carve((size_t)E * 4);
  int* part    = (int*)carve(128 * 4);
  int* partEx  = (int*)carve(128 * 4);
  int* assign0 = (int*)carve((size_t)N * 4);
  int* assign1 = (int*)carve((size_t)TF * 4);

  auto gemmGrid = [](int n) { return (n + 127) / 128; };
  const int HH = H * H;

  // ---- CSR + histograms ----
  hipMemsetAsync(z0, 0, zbytes, stream);
  hist_edges<<<(E + 255) / 256, 256, 0, stream>>>(dst, deg);
  hist_nodes<<<(N + 255) / 256, 256, 0, stream>>>(b0, a0l, cnt1, assign0);
  const int nb1 = (N + 1023) / 1024;
  scan1<<<nb1, 256, 0, stream>>>(deg, offs, part);
  scan2<<<1, 128, 0, stream>>>(part, partEx, nb1);
  scan3<<<(N + 255) / 256, 256, 0, stream>>>(offs, partEx, deg, rdeg, cnt1, rdeg1,
                                             rdegB, assign1);
  scatter_k<<<(E + 255) / 256, 256, 0, stream>>>(src, dst, offs, cursor, srcS);

  // ---- input projection ----
  gemm_k<D0, false, false, true, false><<<gemmGrid(N), 256, 0, stream>>>(
      x0, Wp, nullptr, nullptr, nullptr, nullptr, nullptr, bp, 1, h0, N);

  auto encEdge = [&](const float* Wsarr, const float* Wnarr, const float* barr) {
    for (int l = 0; l < 2; ++l) {
      agg_k<<<N / 4, 256, 0, stream>>>(h0, offs, srcS, rdeg, agg);
      gemm_k<H, true, false, true, false><<<gemmGrid(N), 256, 0, stream>>>(
          h0, Wsarr + l * HH, agg, Wnarr + l * HH, nullptr, nullptr, nullptr,
          barr + l * H, 1, h0, N);
    }
  };
  auto encPlain = [&](float* cur, float* alt, const float* Wsarr, const float* barr,
                      int n) {
    gemm_k<H, false, false, true, false><<<gemmGrid(n), 256, 0, stream>>>(
        cur, Wsarr, nullptr, nullptr, nullptr, nullptr, nullptr, barr, 1, alt, n);
    gemm_k<H, false, false, true, false><<<gemmGrid(n), 256, 0, stream>>>(
        alt, Wsarr + HH, nullptr, nullptr, nullptr, nullptr, nullptr, barr + H, 1,
        cur, n);
  };

  encEdge(e0in_Ws, e0in_Wn, e0in_b);
  float* h1cur = h1a; float* h1alt = h1b;
  float* h2cur = h2a; float* h2alt = h2b;
  encPlain(h1cur, h1alt, e1in_Ws, e1in_b, TF);   // h1a was zeroed
  encPlain(h2cur, h2alt, e2in_Ws, e2in_b, B);    // h2a was zeroed

  for (int step = 0; step < 2; ++step) {
    hipMemsetAsync(p01s, 0, (size_t)TF * H * 4, stream);
    pool_p01<<<400, 128, 0, stream>>>(h0, a0l, b0, p01s);
    mean40<<<B, 128, 0, stream>>>(h1cur, p12);
    gemm_k<H, false, false, false, false><<<gemmGrid(TF), 256, 0, stream>>>(
        h1cur, D1, nullptr, nullptr, nullptr, nullptr, nullptr, nullptr, 0, h1d, TF);
    gemm_k<H, false, false, false, false><<<gemmGrid(B), 256, 0, stream>>>(
        h2cur, D2, nullptr, nullptr, nullptr, nullptr, nullptr, nullptr, 0, h2d, B);
    // n0 = relu(h0@A0 + (h1@D1)[assign0] + ib0)   (in-place on h0)
    gemm_k<H, false, true, true, false><<<gemmGrid(N), 256, 0, stream>>>(
        h0, A0, nullptr, nullptr, nullptr, h1d, assign0, ib0, 1, h0, N);
    // n1 = relu(h1@A1 + mean_p01@U0 + (h2@D2)[assign1] + ib1)
    gemm_k<H, true, true, true, true><<<gemmGrid(TF), 256, 0, stream>>>(
        h1cur, A1, p01s, U0, rdeg1, h2d, assign1, ib1, 1, h1alt, TF);
    // n2 = relu(h2@A2 + p12@U1 + ib2)
    gemm_k<H, true, false, true, false><<<gemmGrid(B), 256, 0, stream>>>(
        h2cur, A2, p12, U1, nullptr, nullptr, nullptr, ib2, 1, h2alt, B);
    { float* tsw = h1cur; h1cur = h1alt; h1alt = tsw; }
    { float* tsw = h2cur; h2cur = h2alt; h2alt = tsw; }
    encEdge(enc0_Ws, enc0_Wn, enc0_b);
    encPlain(h1cur, h1alt, enc1_Ws, enc1_b, TF);
    encPlain(h2cur, h2alt, enc2_Ws, enc2_b, B);
  }

  pool_g0<<<400, 128, 0, stream>>>(h0, b0, g0s);
  mean40<<<B, 128, 0, stream>>>(h1cur, g1);
  head_k<<<B, 128, 0, stream>>>(g0s, rdegB, g1, h2cur, H1w, hb1, H2w, hb2, out);
}

// Round 4
// 1769.300 us; speedup vs baseline: 1.5707x; 1.5707x over previous
//
#include <hip/hip_runtime.h>

namespace {

constexpr int N   = 100000;
constexpr int E   = 600000;
constexpr int B   = 50;
constexpr int F   = 40;
constexpr int TF  = B * F;     // 2000
constexpr int D0  = 64;
constexpr int H   = 128;
constexpr int C   = 2;

typedef __attribute__((ext_vector_type(8))) __bf16 bf16x8;
typedef __attribute__((ext_vector_type(8))) unsigned short us8;
typedef __attribute__((ext_vector_type(4))) float f32x4;

// ---- split-bf16 helpers: x ~ hi + lo, packed as u32 (hi<<16 | lo) ----
__device__ __forceinline__ unsigned bfr(float x) {
  unsigned u = __float_as_uint(x);
  return (u + 0x7FFFu + ((u >> 16) & 1u)) >> 16;
}
__device__ __forceinline__ unsigned packhl(float x) {
  unsigned h = bfr(x);
  float hf = __uint_as_float(h << 16);
  unsigned l = bfr(x - hf);
  return (h << 16) | l;
}
__device__ __forceinline__ float unpackhl(unsigned p) {
  return __uint_as_float(p & 0xFFFF0000u) + __uint_as_float(p << 16);
}

// ---------------- histograms / CSR build ----------------

__global__ void hist_edges(const int* __restrict__ dst, int* __restrict__ deg) {
  int e = blockIdx.x * 256 + threadIdx.x;
  if (e < E) atomicAdd(&deg[dst[e]], 1);
}

__global__ void hist_nodes(const int* __restrict__ b0, const int* __restrict__ a0l,
                           int* __restrict__ cnt1, int* __restrict__ assign0) {
  __shared__ int lh[TF];
  int t = threadIdx.x;
  for (int j = t; j < TF; j += 256) lh[j] = 0;
  __syncthreads();
  int i = blockIdx.x * 256 + t;
  if (i < N) {
    int g = b0[i];
    int a = g * F + a0l[i];
    assign0[i] = a;
    atomicAdd(&lh[a], 1);
  }
  __syncthreads();
  for (int j = t; j < TF; j += 256) {
    int c = lh[j];
    if (c) atomicAdd(&cnt1[j], c);
  }
}

__global__ void scan1(const int* __restrict__ cnt, int* __restrict__ offs,
                      int* __restrict__ part) {
  __shared__ int lds[256];
  int t = threadIdx.x;
  int base = blockIdx.x * 1024 + t * 4;
  int v[4];
#pragma unroll
  for (int j = 0; j < 4; ++j) v[j] = (base + j < N) ? cnt[base + j] : 0;
  int s = v[0] + v[1] + v[2] + v[3];
  lds[t] = s;
  __syncthreads();
  for (int off = 1; off < 256; off <<= 1) {
    int x = (t >= off) ? lds[t - off] : 0;
    __syncthreads();
    lds[t] += x;
    __syncthreads();
  }
  int ex = lds[t] - s;
  if (t == 255) part[blockIdx.x] = lds[255];
  int run = ex;
#pragma unroll
  for (int j = 0; j < 4; ++j) {
    if (base + j < N) offs[base + j] = run;
    run += v[j];
  }
}

__global__ void scan2(const int* __restrict__ part, int* __restrict__ partEx, int nb) {
  __shared__ int lds[128];
  int t = threadIdx.x;
  int s = (t < nb) ? part[t] : 0;
  lds[t] = s;
  __syncthreads();
  for (int off = 1; off < 128; off <<= 1) {
    int x = (t >= off) ? lds[t - off] : 0;
    __syncthreads();
    lds[t] += x;
    __syncthreads();
  }
  partEx[t] = lds[t] - s;
}

__global__ void scan3(int* __restrict__ offs, const int* __restrict__ partEx,
                      const int* __restrict__ deg, float* __restrict__ rdeg,
                      const int* __restrict__ cnt1, float* __restrict__ rdeg1,
                      float* __restrict__ rdegB, int* __restrict__ assign1) {
  int i = blockIdx.x * 256 + threadIdx.x;
  if (i < N) {
    offs[i] += partEx[i >> 10];
    rdeg[i] = 1.0f / fmaxf((float)deg[i], 1.0f);
    if (i == 0) offs[N] = E;
    if (i < TF) { rdeg1[i] = 1.0f / fmaxf((float)cnt1[i], 1.0f); assign1[i] = i / F; }
    if (i < B) {
      int s = 0;
      for (int f = 0; f < F; ++f) s += cnt1[i * F + f];
      rdegB[i] = 1.0f / fmaxf((float)s, 1.0f);
    }
  }
}

__global__ void scatter_k(const int* __restrict__ src, const int* __restrict__ dst,
                          const int* __restrict__ offs, int* __restrict__ cursor,
                          int* __restrict__ srcS) {
  int e = blockIdx.x * 256 + threadIdx.x;
  if (e < E) {
    int d = dst[e];
    int pos = offs[d] + atomicAdd(&cursor[d], 1);
    srcS[pos] = src[e];
  }
}

// ---- weight conversion: fp32 [k][c] -> transposed split-bf16 hi/lo [c][k] ----
struct WPtrs { const float* w[9]; };
__global__ void conv_w(WPtrs wp, unsigned short* __restrict__ wt) {
  int i = blockIdx.x >> 6;                         // matrix index
  int e = (blockIdx.x & 63) * 256 + threadIdx.x;   // 0..16383
  int k = e >> 7, c = e & 127;
  float x = wp.w[i][e];
  unsigned h = bfr(x);
  float hf = __uint_as_float(h << 16);
  unsigned l = bfr(x - hf);
  wt[(size_t)i * 32768 + c * 128 + k] = (unsigned short)h;
  wt[(size_t)i * 32768 + 16384 + c * 128 + k] = (unsigned short)l;
}

// ---------------- edge aggregation (packed hi/lo activations) ----------------
__global__ void agg_k(const unsigned* __restrict__ hp, const int* __restrict__ offs,
                      const int* __restrict__ srcS, const float* __restrict__ rdeg,
                      unsigned* __restrict__ outp) {
  int wid = blockIdx.x * 4 + (threadIdx.x >> 6);
  int lane = threadIdx.x & 63;
  if (wid >= N) return;
  int o0 = offs[wid], o1 = offs[wid + 1];
  float ax = 0.f, ay = 0.f, bx = 0.f, by = 0.f;
  int e = o0;
  for (; e + 1 < o1; e += 2) {
    int s0 = srcS[e], s1 = srcS[e + 1];
    uint2 v0 = ((const uint2*)(hp + (size_t)s0 * H))[lane];
    uint2 v1 = ((const uint2*)(hp + (size_t)s1 * H))[lane];
    ax += unpackhl(v0.x); ay += unpackhl(v0.y);
    bx += unpackhl(v1.x); by += unpackhl(v1.y);
  }
  if (e < o1) {
    int s0 = srcS[e];
    uint2 v0 = ((const uint2*)(hp + (size_t)s0 * H))[lane];
    ax += unpackhl(v0.x); ay += unpackhl(v0.y);
  }
  float sc = rdeg[wid];
  uint2 r;
  r.x = packhl((ax + bx) * sc);
  r.y = packhl((ay + by) * sc);
  ((uint2*)(outp + (size_t)wid * H))[lane] = r;
}

// ---------------- split-bf16 MFMA GEMM (N-row layers) ----------------
// out = relu( A@W1 [+ Agg@W2] [+ Gt[Gidx]] + bias ), A/Agg/out packed u32 hi/lo.
// No LDS: A-frags 16B/lane (lanes 0/16/32/48 cover one 64B line), W-frags from
// L2-resident transposed weights. acc += Ahi*Whi + Ahi*Wlo + Alo*Whi.
__device__ __forceinline__ void afrag(const unsigned* ap, bf16x8& hi, bf16x8& lo) {
  uint4 q0 = *(const uint4*)ap;
  uint4 q1 = *(const uint4*)(ap + 4);
  us8 h, l;
  h[0] = (unsigned short)(q0.x >> 16); l[0] = (unsigned short)q0.x;
  h[1] = (unsigned short)(q0.y >> 16); l[1] = (unsigned short)q0.y;
  h[2] = (unsigned short)(q0.z >> 16); l[2] = (unsigned short)q0.z;
  h[3] = (unsigned short)(q0.w >> 16); l[3] = (unsigned short)q0.w;
  h[4] = (unsigned short)(q1.x >> 16); l[4] = (unsigned short)q1.x;
  h[5] = (unsigned short)(q1.y >> 16); l[5] = (unsigned short)q1.y;
  h[6] = (unsigned short)(q1.z >> 16); l[6] = (unsigned short)q1.z;
  h[7] = (unsigned short)(q1.w >> 16); l[7] = (unsigned short)q1.w;
  hi = __builtin_bit_cast(bf16x8, h);
  lo = __builtin_bit_cast(bf16x8, l);
}

template <bool AGG, bool GATH>
__global__ __launch_bounds__(256)
void mgemm(const unsigned* __restrict__ Ap, const unsigned short* __restrict__ W1,
           const unsigned* __restrict__ Bp, const unsigned short* __restrict__ W2,
           const float* __restrict__ Gt, const int* __restrict__ Gidx,
           const float* __restrict__ bias, unsigned* __restrict__ outp, int n) {
  const int t = threadIdx.x, wv = t >> 6, ln = t & 63;
  const int row0 = blockIdx.x * 128 + wv * 32;
  const int lm = ln & 15, kg = ln >> 4;
  int ar0 = row0 + lm;       // A-load row, m-frag 0
  int ar1 = row0 + 16 + lm;  // m-frag 1
  if (ar0 >= n) ar0 = 0;
  if (ar1 >= n) ar1 = 0;
  f32x4 acc[2][8];
#pragma unroll
  for (int i = 0; i < 2; ++i)
#pragma unroll
    for (int j = 0; j < 8; ++j) acc[i][j] = (f32x4){0.f, 0.f, 0.f, 0.f};

  const int npass = AGG ? 2 : 1;
  for (int pass = 0; pass < npass; ++pass) {
    const unsigned* A = (AGG && pass) ? Bp : Ap;
    const unsigned short* W = (AGG && pass) ? W2 : W1;
    for (int ks = 0; ks < 4; ++ks) {
      const int kk = ks * 32 + kg * 8;
      bf16x8 a0h, a0l, a1h, a1l;
      afrag(A + (size_t)ar0 * H + kk, a0h, a0l);
      afrag(A + (size_t)ar1 * H + kk, a1h, a1l);
#pragma unroll
      for (int nf = 0; nf < 8; ++nf) {
        const unsigned short* wp = W + (nf * 16 + lm) * H + kk;
        bf16x8 wh = *(const bf16x8*)wp;
        bf16x8 wl = *(const bf16x8*)(wp + 16384);
        acc[0][nf] = __builtin_amdgcn_mfma_f32_16x16x32_bf16(a0h, wh, acc[0][nf], 0, 0, 0);
        acc[0][nf] = __builtin_amdgcn_mfma_f32_16x16x32_bf16(a0h, wl, acc[0][nf], 0, 0, 0);
        acc[0][nf] = __builtin_amdgcn_mfma_f32_16x16x32_bf16(a0l, wh, acc[0][nf], 0, 0, 0);
        acc[1][nf] = __builtin_amdgcn_mfma_f32_16x16x32_bf16(a1h, wh, acc[1][nf], 0, 0, 0);
        acc[1][nf] = __builtin_amdgcn_mfma_f32_16x16x32_bf16(a1h, wl, acc[1][nf], 0, 0, 0);
        acc[1][nf] = __builtin_amdgcn_mfma_f32_16x16x32_bf16(a1l, wh, acc[1][nf], 0, 0, 0);
      }
    }
  }

  float bs[8];
#pragma unroll
  for (int nf = 0; nf < 8; ++nf) bs[nf] = bias[nf * 16 + lm];
#pragma unroll
  for (int mf = 0; mf < 2; ++mf)
#pragma unroll
    for (int rr = 0; rr < 4; ++rr) {
      int row = row0 + mf * 16 + kg * 4 + rr;  // D: row=(lane>>4)*4+reg, col=lane&15
      if (row < n) {
        const float* grow = GATH ? (Gt + (size_t)Gidx[row] * H) : nullptr;
#pragma unroll
        for (int nf = 0; nf < 8; ++nf) {
          float v = acc[mf][nf][rr] + bs[nf];
          if (GATH) v += grow[nf * 16 + lm];
          v = fmaxf(v, 0.f);
          outp[(size_t)row * H + nf * 16 + lm] = packhl(v);
        }
      }
    }
}

// ---------------- generic fused fp32 GEMM (small layers + projection) ----------------
// R2 single-buffer version (76 VGPR, known-good); WRHL writes packed hi/lo u32.
template <int K, bool AGG, bool GATH, bool RELU, bool SCALE, bool WRHL>
__global__ __launch_bounds__(256)
void gemm_k(const float* __restrict__ A, const float* __restrict__ W1,
            const float* __restrict__ Agg, const float* __restrict__ W2,
            const float* __restrict__ ascale,
            const float* __restrict__ Gt, const int* __restrict__ Gidx,
            const float* __restrict__ bias, int hasBias,
            float* __restrict__ out, int n) {
  constexpr int BM = 128, KC = 16;
  __shared__ float As[KC][BM + 4];
  __shared__ float Ws[KC][H + 4];
  const int t = threadIdx.x;
  const int tx = t & 15, ty = t >> 4;
  const int row0 = blockIdx.x * BM;
  float acc[8][8];
#pragma unroll
  for (int r = 0; r < 8; ++r)
#pragma unroll
    for (int c = 0; c < 8; ++c) acc[r][c] = 0.f;

  const int sr = t >> 1;
  const int sk = (t & 1) * 8;
  const int wk = t >> 4;
  const int wc = (t & 15) * 8;

  for (int pass = 0; pass < (AGG ? 2 : 1); ++pass) {
    const float* Ain = (AGG && pass) ? Agg : A;
    const float* Win = (AGG && pass) ? W2 : W1;
    for (int k0 = 0; k0 < K; k0 += KC) {
      float4 a0 = make_float4(0, 0, 0, 0), a1 = make_float4(0, 0, 0, 0);
      int r = row0 + sr;
      if (r < n) {
        const float* ap = Ain + (size_t)r * K + k0 + sk;
        a0 = *(const float4*)ap;
        a1 = *(const float4*)(ap + 4);
        if (AGG && SCALE && pass) {
          float sc = ascale[r];
          a0.x *= sc; a0.y *= sc; a0.z *= sc; a0.w *= sc;
          a1.x *= sc; a1.y *= sc; a1.z *= sc; a1.w *= sc;
        }
      }
      const float* wp = Win + (size_t)(k0 + wk) * H + wc;
      float4 w0 = *(const float4*)wp;
      float4 w1 = *(const float4*)(wp + 4);
      __syncthreads();
      As[sk + 0][sr] = a0.x; As[sk + 1][sr] = a0.y;
      As[sk + 2][sr] = a0.z; As[sk + 3][sr] = a0.w;
      As[sk + 4][sr] = a1.x; As[sk + 5][sr] = a1.y;
      As[sk + 6][sr] = a1.z; As[sk + 7][sr] = a1.w;
      *(float4*)&Ws[wk][wc] = w0;
      *(float4*)&Ws[wk][wc + 4] = w1;
      __syncthreads();
#pragma unroll
      for (int k = 0; k < KC; ++k) {
        float4 av0 = *(const float4*)&As[k][ty * 8];
        float4 av1 = *(const float4*)&As[k][ty * 8 + 4];
        float4 bv0 = *(const float4*)&Ws[k][tx * 8];
        float4 bv1 = *(const float4*)&Ws[k][tx * 8 + 4];
        float a_[8] = {av0.x, av0.y, av0.z, av0.w, av1.x, av1.y, av1.z, av1.w};
        float b_[8] = {bv0.x, bv0.y, bv0.z, bv0.w, bv1.x, bv1.y, bv1.z, bv1.w};
#pragma unroll
        for (int rr = 0; rr < 8; ++rr)
#pragma unroll
          for (int cc = 0; cc < 8; ++cc) acc[rr][cc] += a_[rr] * b_[cc];
      }
    }
  }

#pragma unroll
  for (int rr = 0; rr < 8; ++rr) {
    int row = row0 + ty * 8 + rr;
    if (row >= n) continue;
    const float* grow = nullptr;
    if (GATH) grow = Gt + (size_t)Gidx[row] * H;
    float v[8];
#pragma unroll
    for (int cc = 0; cc < 8; ++cc) {
      int col = tx * 8 + cc;
      float x = acc[rr][cc];
      if (hasBias) x += bias[col];
      if (GATH) x += grow[col];
      if (RELU) x = fmaxf(x, 0.f);
      v[cc] = x;
    }
    if (WRHL) {
      unsigned* op = (unsigned*)out + (size_t)row * H + tx * 8;
      *(uint4*)op = make_uint4(packhl(v[0]), packhl(v[1]), packhl(v[2]), packhl(v[3]));
      *(uint4*)(op + 4) = make_uint4(packhl(v[4]), packhl(v[5]), packhl(v[6]), packhl(v[7]));
    } else {
      float* op = out + (size_t)row * H + tx * 8;
      *(float4*)op = make_float4(v[0], v[1], v[2], v[3]);
      *(float4*)(op + 4) = make_float4(v[4], v[5], v[6], v[7]);
    }
  }
}

// ---------------- pooling (packed h0) ----------------
__global__ void pool_p01(const unsigned* __restrict__ hp, const int* __restrict__ a0l,
                         const int* __restrict__ b0, float* __restrict__ p01s) {
  __shared__ float acc[F][H];
  int t = threadIdx.x;  // 128
#pragma unroll
  for (int f = 0; f < F; ++f) acc[f][t] = 0.f;
  int rowbase = blockIdx.x * 250;
  for (int i = 0; i < 250; ++i) {
    int r = rowbase + i;
    acc[a0l[r]][t] += unpackhl(hp[(size_t)r * H + t]);
  }
  int g = b0[rowbase];
#pragma unroll
  for (int f = 0; f < F; ++f)
    atomicAdd(&p01s[((size_t)(g * F + f)) * H + t], acc[f][t]);
}

__global__ void pool_g0(const unsigned* __restrict__ hp, const int* __restrict__ b0,
                        float* __restrict__ g0s) {
  int t = threadIdx.x;
  int rowbase = blockIdx.x * 250;
  float a = 0.f;
  for (int i = 0; i < 250; ++i) a += unpackhl(hp[(size_t)(rowbase + i) * H + t]);
  atomicAdd(&g0s[(size_t)b0[rowbase] * H + t], a);
}

__global__ void mean40(const float* __restrict__ hin, float* __restrict__ outp) {
  int t = threadIdx.x, g = blockIdx.x;
  float a = 0.f;
  for (int i = 0; i < F; ++i) a += hin[(size_t)(g * F + i) * H + t];
  outp[(size_t)g * H + t] = a * (1.0f / F);
}

// ---------------- head MLP ----------------
__global__ void head_k(const float* __restrict__ g0s, const float* __restrict__ rdegB,
                       const float* __restrict__ g1, const float* __restrict__ h2,
                       const float* __restrict__ W1h, const float* __restrict__ b1h,
                       const float* __restrict__ W2h, const float* __restrict__ b2h,
                       float* __restrict__ out) {
  __shared__ float gv[3 * H];
  __shared__ float z[H];
  int b = blockIdx.x, t = threadIdx.x;
  gv[t] = g0s[(size_t)b * H + t] * rdegB[b];
  gv[H + t] = g1[(size_t)b * H + t];
  gv[2 * H + t] = h2[(size_t)b * H + t];
  __syncthreads();
  float s = b1h[t];
  for (int k = 0; k < 3 * H; ++k) s += gv[k] * W1h[k * H + t];
  z[t] = fmaxf(s, 0.f);
  __syncthreads();
  if (t < C) {
    float o = b2h[t];
    for (int k = 0; k < H; ++k) o += z[k] * W2h[k * C + t];
    out[b * C + t] = o;
  }
}

}  // namespace

extern "C" void kernel_launch(void* const* d_in, const int* in_sizes, int n_in,
                              void* d_out, int out_size, void* d_ws, size_t ws_size,
                              hipStream_t stream) {
  (void)in_sizes; (void)n_in; (void)out_size; (void)ws_size;
  const float* x0   = (const float*)d_in[0];
  const int*   ei   = (const int*)d_in[1];
  const int*   src  = ei;
  const int*   dst  = ei + E;
  const int*   b0   = (const int*)d_in[2];
  const int*   a0l  = (const int*)d_in[3];
  const float* Wp   = (const float*)d_in[4];
  const float* bp   = (const float*)d_in[5];
  const float* e0in_Ws = (const float*)d_in[6];
  const float* e0in_Wn = (const float*)d_in[7];
  const float* e0in_b  = (const float*)d_in[8];
  const float* enc0_Ws = (const float*)d_in[9];
  const float* enc0_Wn = (const float*)d_in[10];
  const float* enc0_b  = (const float*)d_in[11];
  const float* e1in_Ws = (const float*)d_in[12];
  const float* e1in_b  = (const float*)d_in[13];
  const float* e2in_Ws = (const float*)d_in[14];
  const float* e2in_b  = (const float*)d_in[15];
  const float* enc1_Ws = (const float*)d_in[16];
  const float* enc1_b  = (const float*)d_in[17];
  const float* enc2_Ws = (const float*)d_in[18];
  const float* enc2_b  = (const float*)d_in[19];
  const float* A0 = (const float*)d_in[20];
  const float* A1 = (const float*)d_in[21];
  const float* A2 = (const float*)d_in[22];
  const float* U0 = (const float*)d_in[23];
  const float* U1 = (const float*)d_in[24];
  const float* D1 = (const float*)d_in[25];
  const float* D2 = (const float*)d_in[26];
  const float* ib0 = (const float*)d_in[27];
  const float* ib1 = (const float*)d_in[28];
  const float* ib2 = (const float*)d_in[29];
  const float* H1w = (const float*)d_in[30];
  const float* hb1 = (const float*)d_in[31];
  const float* H2w = (const float*)d_in[32];
  const float* hb2 = (const float*)d_in[33];
  float* out = (float*)d_out;

  // ---- workspace carve ----
  char* p = (char*)d_ws;
  auto carve = [&](size_t bytes) {
    char* r = p;
    p += (bytes + 255) & ~(size_t)255;
    return r;
  };
  char* z0 = p;  // zeroed-every-call region
  int*   deg    = (int*)carve((size_t)N * 4);
  int*   cursor = (int*)carve((size_t)N * 4);
  int*   cnt1   = (int*)carve((size_t)TF * 4);
  float* h1a    = (float*)carve((size_t)TF * H * 4);
  float* h2a    = (float*)carve((size_t)B * H * 4);
  float* g0s    = (float*)carve((size_t)B * H * 4);
  size_t zbytes = (size_t)(p - z0);
  unsigned* h0p  = (unsigned*)carve((size_t)N * H * 4);
  unsigned* aggp = (unsigned*)carve((size_t)N * H * 4);
  float* h1b  = (float*)carve((size_t)TF * H * 4);
  float* h1d  = (float*)carve((size_t)TF * H * 4);
  float* p01s = (float*)carve((size_t)TF * H * 4);
  float* h2b  = (float*)carve((size_t)B * H * 4);
  float* h2d  = (float*)carve((size_t)B * H * 4);
  float* p12  = (float*)carve((size_t)B * H * 4);
  float* g1   = (float*)carve((size_t)B * H * 4);
  float* rdeg = (float*)carve((size_t)N * 4);
  float* rdeg1 = (float*)carve((size_t)TF * 4);
  float* rdegB = (float*)carve(64 * 4);
  int* offs    = (int*)carve((size_t)(N + 64) * 4);
  int* srcS    = (int*)carve((size_t)E * 4);
  int* part    = (int*)carve(128 * 4);
  int* partEx  = (int*)carve(128 * 4);
  int* assign0 = (int*)carve((size_t)N * 4);
  int* assign1 = (int*)carve((size_t)TF * 4);
  unsigned short* wt = (unsigned short*)carve((size_t)9 * 32768 * 2);

  auto gemmGrid = [](int n) { return (n + 127) / 128; };
  const int HH = H * H;
  const int MG = (N + 127) / 128;  // 782

  // ---- CSR + histograms + weight split ----
  hipMemsetAsync(z0, 0, zbytes, stream);
  hist_edges<<<(E + 255) / 256, 256, 0, stream>>>(dst, deg);
  hist_nodes<<<(N + 255) / 256, 256, 0, stream>>>(b0, a0l, cnt1, assign0);
  const int nb1 = (N + 1023) / 1024;
  scan1<<<nb1, 256, 0, stream>>>(deg, offs, part);
  scan2<<<1, 128, 0, stream>>>(part, partEx, nb1);
  scan3<<<(N + 255) / 256, 256, 0, stream>>>(offs, partEx, deg, rdeg, cnt1, rdeg1,
                                             rdegB, assign1);
  scatter_k<<<(E + 255) / 256, 256, 0, stream>>>(src, dst, offs, cursor, srcS);
  {
    WPtrs wp;
    wp.w[0] = e0in_Ws;      wp.w[1] = e0in_Ws + HH;
    wp.w[2] = e0in_Wn;      wp.w[3] = e0in_Wn + HH;
    wp.w[4] = enc0_Ws;      wp.w[5] = enc0_Ws + HH;
    wp.w[6] = enc0_Wn;      wp.w[7] = enc0_Wn + HH;
    wp.w[8] = A0;
    conv_w<<<9 * 64, 256, 0, stream>>>(wp, wt);
  }

  // ---- input projection (fp32 GEMM, writes packed hi/lo) ----
  gemm_k<D0, false, false, true, false, true><<<MG, 256, 0, stream>>>(
      x0, Wp, nullptr, nullptr, nullptr, nullptr, nullptr, bp, 1, (float*)h0p, N);

  auto encEdgeM = [&](int wsIdx, int wnIdx, const float* barr) {
    for (int l = 0; l < 2; ++l) {
      agg_k<<<N / 4, 256, 0, stream>>>(h0p, offs, srcS, rdeg, aggp);
      mgemm<true, false><<<MG, 256, 0, stream>>>(
          h0p, wt + (size_t)(wsIdx + l) * 32768, aggp,
          wt + (size_t)(wnIdx + l) * 32768, nullptr, nullptr, barr + l * H, h0p, N);
    }
  };
  auto encPlain = [&](float* cur, float* alt, const float* Wsarr, const float* barr,
                      int n) {
    gemm_k<H, false, false, true, false, false><<<gemmGrid(n), 256, 0, stream>>>(
        cur, Wsarr, nullptr, nullptr, nullptr, nullptr, nullptr, barr, 1, alt, n);
    gemm_k<H, false, false, true, false, false><<<gemmGrid(n), 256, 0, stream>>>(
        alt, Wsarr + HH, nullptr, nullptr, nullptr, nullptr, nullptr, barr + H, 1,
        cur, n);
  };

  encEdgeM(0, 2, e0in_b);
  float* h1cur = h1a; float* h1alt = h1b;
  float* h2cur = h2a; float* h2alt = h2b;
  encPlain(h1cur, h1alt, e1in_Ws, e1in_b, TF);   // h1a was zeroed
  encPlain(h2cur, h2alt, e2in_Ws, e2in_b, B);    // h2a was zeroed

  for (int step = 0; step < 2; ++step) {
    hipMemsetAsync(p01s, 0, (size_t)TF * H * 4, stream);
    pool_p01<<<400, 128, 0, stream>>>(h0p, a0l, b0, p01s);
    mean40<<<B, 128, 0, stream>>>(h1cur, p12);
    gemm_k<H, false, false, false, false, false><<<gemmGrid(TF), 256, 0, stream>>>(
        h1cur, D1, nullptr, nullptr, nullptr, nullptr, nullptr, nullptr, 0, h1d, TF);
    gemm_k<H, false, false, false, false, false><<<gemmGrid(B), 256, 0, stream>>>(
        h2cur, D2, nullptr, nullptr, nullptr, nullptr, nullptr, nullptr, 0, h2d, B);
    // n0 = relu(h0@A0 + (h1@D1)[assign0] + ib0)   (in-place on h0p, MFMA)
    mgemm<false, true><<<MG, 256, 0, stream>>>(
        h0p, wt + (size_t)8 * 32768, nullptr, nullptr, h1d, assign0, ib0, h0p, N);
    // n1 = relu(h1@A1 + mean_p01@U0 + (h2@D2)[assign1] + ib1)
    gemm_k<H, true, true, true, true, false><<<gemmGrid(TF), 256, 0, stream>>>(
        h1cur, A1, p01s, U0, rdeg1, h2d, assign1, ib1, 1, h1alt, TF);
    // n2 = relu(h2@A2 + p12@U1 + ib2)
    gemm_k<H, true, false, true, false, false><<<gemmGrid(B), 256, 0, stream>>>(
        h2cur, A2, p12, U1, nullptr, nullptr, nullptr, ib2, 1, h2alt, B);
    { float* tsw = h1cur; h1cur = h1alt; h1alt = tsw; }
    { float* tsw = h2cur; h2cur = h2alt; h2alt = tsw; }
    encEdgeM(4, 6, enc0_b);
    encPlain(h1cur, h1alt, enc1_Ws, enc1_b, TF);
    encPlain(h2cur, h2alt, enc2_Ws, enc2_b, B);
  }

  pool_g0<<<400, 128, 0, stream>>>(h0p, b0, g0s);
  mean40<<<B, 128, 0, stream>>>(h1cur, g1);
  head_k<<<B, 128, 0, stream>>>(g0s, rdegB, g1, h2cur, H1w, hb1, H2w, hb2, out);
}

// Round 5
// 1477.754 us; speedup vs baseline: 1.8805x; 1.1973x over previous
//
#include <hip/hip_runtime.h>

namespace {

constexpr int N   = 100000;
constexpr int E   = 600000;
constexpr int B   = 50;
constexpr int F   = 40;
constexpr int TF  = B * F;     // 2000
constexpr int D0  = 64;
constexpr int H   = 128;
constexpr int C   = 2;

typedef __attribute__((ext_vector_type(8))) __bf16 bf16x8;
typedef __attribute__((ext_vector_type(8))) unsigned short us8;
typedef __attribute__((ext_vector_type(4))) float f32x4;

__device__ __forceinline__ float asf(unsigned u) { return __uint_as_float(u); }
// round-to-nearest-even fp32 -> bf16 (returns low 16 bits)
__device__ __forceinline__ unsigned bfr(float x) {
  unsigned u = __float_as_uint(x);
  return (u + 0x7FFFu + ((u >> 16) & 1u)) >> 16;
}

// ---------------- histograms / CSR build ----------------

__global__ void hist_edges(const int* __restrict__ dst, int* __restrict__ deg) {
  int e = blockIdx.x * 256 + threadIdx.x;
  if (e < E) atomicAdd(&deg[dst[e]], 1);
}

__global__ void hist_nodes(const int* __restrict__ b0, const int* __restrict__ a0l,
                           int* __restrict__ cnt1, int* __restrict__ assign0) {
  __shared__ int lh[TF];
  int t = threadIdx.x;
  for (int j = t; j < TF; j += 256) lh[j] = 0;
  __syncthreads();
  int i = blockIdx.x * 256 + t;
  if (i < N) {
    int g = b0[i];
    int a = g * F + a0l[i];
    assign0[i] = a;
    atomicAdd(&lh[a], 1);
  }
  __syncthreads();
  for (int j = t; j < TF; j += 256) {
    int c = lh[j];
    if (c) atomicAdd(&cnt1[j], c);
  }
}

__global__ void scan1(const int* __restrict__ cnt, int* __restrict__ offs,
                      int* __restrict__ part) {
  __shared__ int lds[256];
  int t = threadIdx.x;
  int base = blockIdx.x * 1024 + t * 4;
  int v[4];
#pragma unroll
  for (int j = 0; j < 4; ++j) v[j] = (base + j < N) ? cnt[base + j] : 0;
  int s = v[0] + v[1] + v[2] + v[3];
  lds[t] = s;
  __syncthreads();
  for (int off = 1; off < 256; off <<= 1) {
    int x = (t >= off) ? lds[t - off] : 0;
    __syncthreads();
    lds[t] += x;
    __syncthreads();
  }
  int ex = lds[t] - s;
  if (t == 255) part[blockIdx.x] = lds[255];
  int run = ex;
#pragma unroll
  for (int j = 0; j < 4; ++j) {
    if (base + j < N) offs[base + j] = run;
    run += v[j];
  }
}

__global__ void scan2(const int* __restrict__ part, int* __restrict__ partEx, int nb) {
  __shared__ int lds[128];
  int t = threadIdx.x;
  int s = (t < nb) ? part[t] : 0;
  lds[t] = s;
  __syncthreads();
  for (int off = 1; off < 128; off <<= 1) {
    int x = (t >= off) ? lds[t - off] : 0;
    __syncthreads();
    lds[t] += x;
    __syncthreads();
  }
  partEx[t] = lds[t] - s;
}

__global__ void scan3(int* __restrict__ offs, const int* __restrict__ partEx,
                      const int* __restrict__ deg, float* __restrict__ rdeg,
                      const int* __restrict__ cnt1, float* __restrict__ rdeg1,
                      float* __restrict__ rdegB, int* __restrict__ assign1) {
  int i = blockIdx.x * 256 + threadIdx.x;
  if (i < N) {
    offs[i] += partEx[i >> 10];
    rdeg[i] = 1.0f / fmaxf((float)deg[i], 1.0f);
    if (i == 0) offs[N] = E;
    if (i < TF) { rdeg1[i] = 1.0f / fmaxf((float)cnt1[i], 1.0f); assign1[i] = i / F; }
    if (i < B) {
      int s = 0;
      for (int f = 0; f < F; ++f) s += cnt1[i * F + f];
      rdegB[i] = 1.0f / fmaxf((float)s, 1.0f);
    }
  }
}

__global__ void scatter_k(const int* __restrict__ src, const int* __restrict__ dst,
                          const int* __restrict__ offs, int* __restrict__ cursor,
                          int* __restrict__ srcS) {
  int e = blockIdx.x * 256 + threadIdx.x;
  if (e < E) {
    int d = dst[e];
    int pos = offs[d] + atomicAdd(&cursor[d], 1);
    srcS[pos] = src[e];
  }
}

// ---- weight conversion: fp32 [k][c] -> split-bf16, slice-major, col-permuted ----
// layout per matrix (32768 shorts): hi [ks][c_s][32] at 0, lo at +16384.
// storage slot c_s = (c&7)*16 + (c>>3) holds actual output column c, so that
// mgemm's (nf,lm) fragment covers cols lm*8+nf -> lane-contiguous epilogue.
struct WPtrs { const float* w[9]; };
__global__ void conv_w(WPtrs wp, unsigned short* __restrict__ wt) {
  int i = blockIdx.x >> 6;                         // matrix index
  int e = (blockIdx.x & 63) * 256 + threadIdx.x;   // 0..16383
  int k = e >> 7, c = e & 127;
  float x = wp.w[i][e];
  unsigned h = bfr(x);
  unsigned l = bfr(x - asf(h << 16));
  int cs = (c & 7) * 16 + (c >> 3);
  size_t o = (size_t)i * 32768 + (k >> 5) * 4096 + cs * 32 + (k & 31);
  wt[o] = (unsigned short)h;
  wt[o + 16384] = (unsigned short)l;
}

// ---------------- edge aggregation (hi/lo bf16 planes) ----------------
__global__ void agg_k(const unsigned short* __restrict__ Ah,
                      const unsigned short* __restrict__ Al,
                      const int* __restrict__ offs, const int* __restrict__ srcS,
                      const float* __restrict__ rdeg,
                      unsigned short* __restrict__ Oh, unsigned short* __restrict__ Ol) {
  int wid = blockIdx.x * 4 + (threadIdx.x >> 6);
  int lane = threadIdx.x & 63;
  if (wid >= N) return;
  int o0 = offs[wid], o1 = offs[wid + 1];
  float ax = 0.f, ay = 0.f, bx = 0.f, by = 0.f;
  int e = o0;
  for (; e + 1 < o1; e += 2) {
    size_t r0 = (size_t)srcS[e] * H, r1 = (size_t)srcS[e + 1] * H;
    unsigned h0 = *(const unsigned*)(Ah + r0 + lane * 2);
    unsigned l0 = *(const unsigned*)(Al + r0 + lane * 2);
    unsigned h1 = *(const unsigned*)(Ah + r1 + lane * 2);
    unsigned l1 = *(const unsigned*)(Al + r1 + lane * 2);
    ax += asf(h0 << 16) + asf(l0 << 16);
    ay += asf(h0 & 0xFFFF0000u) + asf(l0 & 0xFFFF0000u);
    bx += asf(h1 << 16) + asf(l1 << 16);
    by += asf(h1 & 0xFFFF0000u) + asf(l1 & 0xFFFF0000u);
  }
  if (e < o1) {
    size_t r0 = (size_t)srcS[e] * H;
    unsigned h0 = *(const unsigned*)(Ah + r0 + lane * 2);
    unsigned l0 = *(const unsigned*)(Al + r0 + lane * 2);
    ax += asf(h0 << 16) + asf(l0 << 16);
    ay += asf(h0 & 0xFFFF0000u) + asf(l0 & 0xFFFF0000u);
  }
  float sc = rdeg[wid];
  float vx = (ax + bx) * sc, vy = (ay + by) * sc;
  unsigned hx = bfr(vx), hy = bfr(vy);
  unsigned lx = bfr(vx - asf(hx << 16)), ly = bfr(vy - asf(hy << 16));
  *(unsigned*)(Oh + (size_t)wid * H + lane * 2) = hx | (hy << 16);
  *(unsigned*)(Ol + (size_t)wid * H + lane * 2) = lx | (ly << 16);
}

// ---------------- split-bf16 MFMA GEMM, LDS-staged weights ----------------
// out = relu( A@W1 [+ Agg@W2] [+ Gt[Gidx]] + bias ); activations = hi/lo planes.
// W k-slices (8KB hi + 8KB lo) double-buffered in LDS; A-frags prefetched 1 step.
template <bool AGG, bool GATH>
__global__ __launch_bounds__(256, 3)
void mgemm(const unsigned short* __restrict__ Ah, const unsigned short* __restrict__ Al,
           const unsigned short* __restrict__ W1,
           const unsigned short* __restrict__ Bh, const unsigned short* __restrict__ Bl,
           const unsigned short* __restrict__ W2,
           const float* __restrict__ Gt, const int* __restrict__ Gidx,
           const float* __restrict__ bias,
           unsigned short* __restrict__ Oh, unsigned short* __restrict__ Ol, int n) {
  __shared__ unsigned short wlds[2][2][4096];  // [buf][hi/lo][slice]
  const int t = threadIdx.x, wv = t >> 6, ln = t & 63;
  const int row0 = blockIdx.x * 128 + wv * 32;
  const int lm = ln & 15, kg = ln >> 4;
  int ar0 = row0 + lm, ar1 = row0 + 16 + lm;
  if (ar0 >= n) ar0 = 0;
  if (ar1 >= n) ar1 = 0;
  const size_t a0off = (size_t)ar0 * H, a1off = (size_t)ar1 * H;

  f32x4 acc[2][8];
#pragma unroll
  for (int i = 0; i < 2; ++i)
#pragma unroll
    for (int j = 0; j < 8; ++j) acc[i][j] = (f32x4){0.f, 0.f, 0.f, 0.f};

  constexpr int NS = AGG ? 8 : 4;
  uint4 sA, sB, sC, sD;          // W-slice staging registers
  bf16x8 a0h[2], a0l[2], a1h[2], a1l[2];

  auto ldst = [&](int s) {       // issue global loads of W slice for step s
    const unsigned short* W = (AGG && s >= 4) ? W2 : W1;
    const unsigned short* ph = W + (s & 3) * 4096;
    sA = *(const uint4*)(ph + t * 8);
    sB = *(const uint4*)(ph + 2048 + t * 8);
    sC = *(const uint4*)(ph + 16384 + t * 8);
    sD = *(const uint4*)(ph + 16384 + 2048 + t * 8);
  };
  auto wrst = [&](int buf) {
    *(uint4*)&wlds[buf][0][t * 8] = sA;
    *(uint4*)&wlds[buf][0][2048 + t * 8] = sB;
    *(uint4*)&wlds[buf][1][t * 8] = sC;
    *(uint4*)&wlds[buf][1][2048 + t * 8] = sD;
  };
  auto loadA = [&](int s, int w) {
    const unsigned short* Xh = (AGG && s >= 4) ? Bh : Ah;
    const unsigned short* Xl = (AGG && s >= 4) ? Bl : Al;
    int kk = (s & 3) * 32 + kg * 8;
    a0h[w] = *(const bf16x8*)(Xh + a0off + kk);
    a0l[w] = *(const bf16x8*)(Xl + a0off + kk);
    a1h[w] = *(const bf16x8*)(Xh + a1off + kk);
    a1l[w] = *(const bf16x8*)(Xl + a1off + kk);
  };

  ldst(0); wrst(0); loadA(0, 0);
  __syncthreads();

#pragma unroll
  for (int s = 0; s < NS; ++s) {
    const int buf = s & 1;
    if (s + 1 < NS) { ldst(s + 1); loadA(s + 1, buf ^ 1); }
#pragma unroll
    for (int nf = 0; nf < 8; ++nf) {
      const int wo = (nf * 16 + lm) * 32 + kg * 8;
      bf16x8 wh = *(const bf16x8*)&wlds[buf][0][wo];
      bf16x8 wl = *(const bf16x8*)&wlds[buf][1][wo];
      acc[0][nf] = __builtin_amdgcn_mfma_f32_16x16x32_bf16(a0h[buf], wh, acc[0][nf], 0, 0, 0);
      acc[0][nf] = __builtin_amdgcn_mfma_f32_16x16x32_bf16(a0h[buf], wl, acc[0][nf], 0, 0, 0);
      acc[0][nf] = __builtin_amdgcn_mfma_f32_16x16x32_bf16(a0l[buf], wh, acc[0][nf], 0, 0, 0);
      acc[1][nf] = __builtin_amdgcn_mfma_f32_16x16x32_bf16(a1h[buf], wh, acc[1][nf], 0, 0, 0);
      acc[1][nf] = __builtin_amdgcn_mfma_f32_16x16x32_bf16(a1h[buf], wl, acc[1][nf], 0, 0, 0);
      acc[1][nf] = __builtin_amdgcn_mfma_f32_16x16x32_bf16(a1l[buf], wh, acc[1][nf], 0, 0, 0);
    }
    if (s + 1 < NS) wrst(buf ^ 1);
    __syncthreads();
  }

  float4 bq0 = *(const float4*)&bias[lm * 8];
  float4 bq1 = *(const float4*)&bias[lm * 8 + 4];
  float bsv[8] = {bq0.x, bq0.y, bq0.z, bq0.w, bq1.x, bq1.y, bq1.z, bq1.w};
#pragma unroll
  for (int mf = 0; mf < 2; ++mf)
#pragma unroll
    for (int rr = 0; rr < 4; ++rr) {
      int row = row0 + mf * 16 + kg * 4 + rr;  // D: row=(lane>>4)*4+reg, col=lane&15
      if (row >= n) continue;
      float gvv[8];
      if (GATH) {
        const float* grow = Gt + (size_t)Gidx[row] * H + lm * 8;
        float4 g0 = *(const float4*)grow;
        float4 g1 = *(const float4*)(grow + 4);
        gvv[0] = g0.x; gvv[1] = g0.y; gvv[2] = g0.z; gvv[3] = g0.w;
        gvv[4] = g1.x; gvv[5] = g1.y; gvv[6] = g1.z; gvv[7] = g1.w;
      }
      us8 hv, lv;
#pragma unroll
      for (int nf = 0; nf < 8; ++nf) {   // actual col = lm*8 + nf
        float v = acc[mf][nf][rr] + bsv[nf];
        if (GATH) v += gvv[nf];
        v = fmaxf(v, 0.f);
        unsigned h = bfr(v);
        hv[nf] = (unsigned short)h;
        lv[nf] = (unsigned short)bfr(v - asf(h << 16));
      }
      *(us8*)(Oh + (size_t)row * H + lm * 8) = hv;
      *(us8*)(Ol + (size_t)row * H + lm * 8) = lv;
    }
}

// ---------------- generic fused fp32 GEMM (small layers + projection) ----------------
template <int K, bool AGG, bool GATH, bool RELU, bool SCALE, bool WRHL>
__global__ __launch_bounds__(256)
void gemm_k(const float* __restrict__ A, const float* __restrict__ W1,
            const float* __restrict__ Agg, const float* __restrict__ W2,
            const float* __restrict__ ascale,
            const float* __restrict__ Gt, const int* __restrict__ Gidx,
            const float* __restrict__ bias, int hasBias,
            float* __restrict__ out, float* __restrict__ outB, int n) {
  constexpr int BM = 128, KC = 16;
  __shared__ float As[KC][BM + 4];
  __shared__ float Ws[KC][H + 4];
  const int t = threadIdx.x;
  const int tx = t & 15, ty = t >> 4;
  const int row0 = blockIdx.x * BM;
  float acc[8][8];
#pragma unroll
  for (int r = 0; r < 8; ++r)
#pragma unroll
    for (int c = 0; c < 8; ++c) acc[r][c] = 0.f;

  const int sr = t >> 1;
  const int sk = (t & 1) * 8;
  const int wk = t >> 4;
  const int wc = (t & 15) * 8;

  for (int pass = 0; pass < (AGG ? 2 : 1); ++pass) {
    const float* Ain = (AGG && pass) ? Agg : A;
    const float* Win = (AGG && pass) ? W2 : W1;
    for (int k0 = 0; k0 < K; k0 += KC) {
      float4 a0 = make_float4(0, 0, 0, 0), a1 = make_float4(0, 0, 0, 0);
      int r = row0 + sr;
      if (r < n) {
        const float* ap = Ain + (size_t)r * K + k0 + sk;
        a0 = *(const float4*)ap;
        a1 = *(const float4*)(ap + 4);
        if (AGG && SCALE && pass) {
          float sc = ascale[r];
          a0.x *= sc; a0.y *= sc; a0.z *= sc; a0.w *= sc;
          a1.x *= sc; a1.y *= sc; a1.z *= sc; a1.w *= sc;
        }
      }
      const float* wp = Win + (size_t)(k0 + wk) * H + wc;
      float4 w0 = *(const float4*)wp;
      float4 w1 = *(const float4*)(wp + 4);
      __syncthreads();
      As[sk + 0][sr] = a0.x; As[sk + 1][sr] = a0.y;
      As[sk + 2][sr] = a0.z; As[sk + 3][sr] = a0.w;
      As[sk + 4][sr] = a1.x; As[sk + 5][sr] = a1.y;
      As[sk + 6][sr] = a1.z; As[sk + 7][sr] = a1.w;
      *(float4*)&Ws[wk][wc] = w0;
      *(float4*)&Ws[wk][wc + 4] = w1;
      __syncthreads();
#pragma unroll
      for (int k = 0; k < KC; ++k) {
        float4 av0 = *(const float4*)&As[k][ty * 8];
        float4 av1 = *(const float4*)&As[k][ty * 8 + 4];
        float4 bv0 = *(const float4*)&Ws[k][tx * 8];
        float4 bv1 = *(const float4*)&Ws[k][tx * 8 + 4];
        float a_[8] = {av0.x, av0.y, av0.z, av0.w, av1.x, av1.y, av1.z, av1.w};
        float b_[8] = {bv0.x, bv0.y, bv0.z, bv0.w, bv1.x, bv1.y, bv1.z, bv1.w};
#pragma unroll
        for (int rr = 0; rr < 8; ++rr)
#pragma unroll
          for (int cc = 0; cc < 8; ++cc) acc[rr][cc] += a_[rr] * b_[cc];
      }
    }
  }

#pragma unroll
  for (int rr = 0; rr < 8; ++rr) {
    int row = row0 + ty * 8 + rr;
    if (row >= n) continue;
    const float* grow = nullptr;
    if (GATH) grow = Gt + (size_t)Gidx[row] * H;
    float v[8];
#pragma unroll
    for (int cc = 0; cc < 8; ++cc) {
      int col = tx * 8 + cc;
      float x = acc[rr][cc];
      if (hasBias) x += bias[col];
      if (GATH) x += grow[col];
      if (RELU) x = fmaxf(x, 0.f);
      v[cc] = x;
    }
    if (WRHL) {
      us8 hv, lv;
#pragma unroll
      for (int cc = 0; cc < 8; ++cc) {
        unsigned h = bfr(v[cc]);
        hv[cc] = (unsigned short)h;
        lv[cc] = (unsigned short)bfr(v[cc] - asf(h << 16));
      }
      *(us8*)((unsigned short*)out + (size_t)row * H + tx * 8) = hv;
      *(us8*)((unsigned short*)outB + (size_t)row * H + tx * 8) = lv;
    } else {
      float* op = out + (size_t)row * H + tx * 8;
      *(float4*)op = make_float4(v[0], v[1], v[2], v[3]);
      *(float4*)(op + 4) = make_float4(v[4], v[5], v[6], v[7]);
    }
  }
}

// ---------------- pooling (hi/lo planes) ----------------
__global__ void pool_p01(const unsigned short* __restrict__ Ah,
                         const unsigned short* __restrict__ Al,
                         const int* __restrict__ a0l, const int* __restrict__ b0,
                         float* __restrict__ p01s) {
  __shared__ float acc[F][H];
  int t = threadIdx.x;  // 128
#pragma unroll
  for (int f = 0; f < F; ++f) acc[f][t] = 0.f;
  int rowbase = blockIdx.x * 250;
  for (int i = 0; i < 250; ++i) {
    size_t r = (size_t)(rowbase + i) * H + t;
    acc[a0l[rowbase + i]][t] += asf((unsigned)Ah[r] << 16) + asf((unsigned)Al[r] << 16);
  }
  int g = b0[rowbase];
#pragma unroll
  for (int f = 0; f < F; ++f)
    atomicAdd(&p01s[((size_t)(g * F + f)) * H + t], acc[f][t]);
}

__global__ void pool_g0(const unsigned short* __restrict__ Ah,
                        const unsigned short* __restrict__ Al,
                        const int* __restrict__ b0, float* __restrict__ g0s) {
  int t = threadIdx.x;
  int rowbase = blockIdx.x * 250;
  float a = 0.f;
  for (int i = 0; i < 250; ++i) {
    size_t r = (size_t)(rowbase + i) * H + t;
    a += asf((unsigned)Ah[r] << 16) + asf((unsigned)Al[r] << 16);
  }
  atomicAdd(&g0s[(size_t)b0[rowbase] * H + t], a);
}

__global__ void mean40(const float* __restrict__ hin, float* __restrict__ outp) {
  int t = threadIdx.x, g = blockIdx.x;
  float a = 0.f;
  for (int i = 0; i < F; ++i) a += hin[(size_t)(g * F + i) * H + t];
  outp[(size_t)g * H + t] = a * (1.0f / F);
}

// ---------------- head MLP ----------------
__global__ void head_k(const float* __restrict__ g0s, const float* __restrict__ rdegB,
                       const float* __restrict__ g1, const float* __restrict__ h2,
                       const float* __restrict__ W1h, const float* __restrict__ b1h,
                       const float* __restrict__ W2h, const float* __restrict__ b2h,
                       float* __restrict__ out) {
  __shared__ float gv[3 * H];
  __shared__ float z[H];
  int b = blockIdx.x, t = threadIdx.x;
  gv[t] = g0s[(size_t)b * H + t] * rdegB[b];
  gv[H + t] = g1[(size_t)b * H + t];
  gv[2 * H + t] = h2[(size_t)b * H + t];
  __syncthreads();
  float s = b1h[t];
  for (int k = 0; k < 3 * H; ++k) s += gv[k] * W1h[k * H + t];
  z[t] = fmaxf(s, 0.f);
  __syncthreads();
  if (t < C) {
    float o = b2h[t];
    for (int k = 0; k < H; ++k) o += z[k] * W2h[k * C + t];
    out[b * C + t] = o;
  }
}

}  // namespace

extern "C" void kernel_launch(void* const* d_in, const int* in_sizes, int n_in,
                              void* d_out, int out_size, void* d_ws, size_t ws_size,
                              hipStream_t stream) {
  (void)in_sizes; (void)n_in; (void)out_size; (void)ws_size;
  const float* x0   = (const float*)d_in[0];
  const int*   ei   = (const int*)d_in[1];
  const int*   src  = ei;
  const int*   dst  = ei + E;
  const int*   b0   = (const int*)d_in[2];
  const int*   a0l  = (const int*)d_in[3];
  const float* Wp   = (const float*)d_in[4];
  const float* bp   = (const float*)d_in[5];
  const float* e0in_Ws = (const float*)d_in[6];
  const float* e0in_Wn = (const float*)d_in[7];
  const float* e0in_b  = (const float*)d_in[8];
  const float* enc0_Ws = (const float*)d_in[9];
  const float* enc0_Wn = (const float*)d_in[10];
  const float* enc0_b  = (const float*)d_in[11];
  const float* e1in_Ws = (const float*)d_in[12];
  const float* e1in_b  = (const float*)d_in[13];
  const float* e2in_Ws = (const float*)d_in[14];
  const float* e2in_b  = (const float*)d_in[15];
  const float* enc1_Ws = (const float*)d_in[16];
  const float* enc1_b  = (const float*)d_in[17];
  const float* enc2_Ws = (const float*)d_in[18];
  const float* enc2_b  = (const float*)d_in[19];
  const float* A0 = (const float*)d_in[20];
  const float* A1 = (const float*)d_in[21];
  const float* A2 = (const float*)d_in[22];
  const float* U0 = (const float*)d_in[23];
  const float* U1 = (const float*)d_in[24];
  const float* D1 = (const float*)d_in[25];
  const float* D2 = (const float*)d_in[26];
  const float* ib0 = (const float*)d_in[27];
  const float* ib1 = (const float*)d_in[28];
  const float* ib2 = (const float*)d_in[29];
  const float* H1w = (const float*)d_in[30];
  const float* hb1 = (const float*)d_in[31];
  const float* H2w = (const float*)d_in[32];
  const float* hb2 = (const float*)d_in[33];
  float* out = (float*)d_out;

  // ---- workspace carve ----
  char* p = (char*)d_ws;
  auto carve = [&](size_t bytes) {
    char* r = p;
    p += (bytes + 255) & ~(size_t)255;
    return r;
  };
  char* z0 = p;  // zeroed-every-call region
  int*   deg    = (int*)carve((size_t)N * 4);
  int*   cursor = (int*)carve((size_t)N * 4);
  int*   cnt1   = (int*)carve((size_t)TF * 4);
  float* h1a    = (float*)carve((size_t)TF * H * 4);
  float* h2a    = (float*)carve((size_t)B * H * 4);
  float* g0s    = (float*)carve((size_t)B * H * 4);
  size_t zbytes = (size_t)(p - z0);
  unsigned short* h0h  = (unsigned short*)carve((size_t)N * H * 2);
  unsigned short* h0l  = (unsigned short*)carve((size_t)N * H * 2);
  unsigned short* aggh = (unsigned short*)carve((size_t)N * H * 2);
  unsigned short* aggl = (unsigned short*)carve((size_t)N * H * 2);
  float* h1b  = (float*)carve((size_t)TF * H * 4);
  float* h1d  = (float*)carve((size_t)TF * H * 4);
  float* p01s = (float*)carve((size_t)TF * H * 4);
  float* h2b  = (float*)carve((size_t)B * H * 4);
  float* h2d  = (float*)carve((size_t)B * H * 4);
  float* p12  = (float*)carve((size_t)B * H * 4);
  float* g1   = (float*)carve((size_t)B * H * 4);
  float* rdeg = (float*)carve((size_t)N * 4);
  float* rdeg1 = (float*)carve((size_t)TF * 4);
  float* rdegB = (float*)carve(64 * 4);
  int* offs    = (int*)carve((size_t)(N + 64) * 4);
  int* srcS    = (int*)carve((size_t)E * 4);
  int* part    = (int*)carve(128 * 4);
  int* partEx  = (int*)carve(128 * 4);
  int* assign0 = (int*)carve((size_t)N * 4);
  int* assign1 = (int*)carve((size_t)TF * 4);
  unsigned short* wt = (unsigned short*)carve((size_t)9 * 32768 * 2);

  auto gemmGrid = [](int n) { return (n + 127) / 128; };
  const int HH = H * H;
  const int MG = (N + 127) / 128;  // 782

  // ---- CSR + histograms + weight split ----
  hipMemsetAsync(z0, 0, zbytes, stream);
  hist_edges<<<(E + 255) / 256, 256, 0, stream>>>(dst, deg);
  hist_nodes<<<(N + 255) / 256, 256, 0, stream>>>(b0, a0l, cnt1, assign0);
  const int nb1 = (N + 1023) / 1024;
  scan1<<<nb1, 256, 0, stream>>>(deg, offs, part);
  scan2<<<1, 128, 0, stream>>>(part, partEx, nb1);
  scan3<<<(N + 255) / 256, 256, 0, stream>>>(offs, partEx, deg, rdeg, cnt1, rdeg1,
                                             rdegB, assign1);
  scatter_k<<<(E + 255) / 256, 256, 0, stream>>>(src, dst, offs, cursor, srcS);
  {
    WPtrs wp;
    wp.w[0] = e0in_Ws;      wp.w[1] = e0in_Ws + HH;
    wp.w[2] = e0in_Wn;      wp.w[3] = e0in_Wn + HH;
    wp.w[4] = enc0_Ws;      wp.w[5] = enc0_Ws + HH;
    wp.w[6] = enc0_Wn;      wp.w[7] = enc0_Wn + HH;
    wp.w[8] = A0;
    conv_w<<<9 * 64, 256, 0, stream>>>(wp, wt);
  }

  // ---- input projection (fp32 GEMM, writes hi/lo planes) ----
  gemm_k<D0, false, false, true, false, true><<<MG, 256, 0, stream>>>(
      x0, Wp, nullptr, nullptr, nullptr, nullptr, nullptr, bp, 1,
      (float*)h0h, (float*)h0l, N);

  auto encEdgeM = [&](int wsIdx, int wnIdx, const float* barr) {
    for (int l = 0; l < 2; ++l) {
      agg_k<<<N / 4, 256, 0, stream>>>(h0h, h0l, offs, srcS, rdeg, aggh, aggl);
      mgemm<true, false><<<MG, 256, 0, stream>>>(
          h0h, h0l, wt + (size_t)(wsIdx + l) * 32768, aggh, aggl,
          wt + (size_t)(wnIdx + l) * 32768, nullptr, nullptr, barr + l * H,
          h0h, h0l, N);
    }
  };
  auto encPlain = [&](float* cur, float* alt, const float* Wsarr, const float* barr,
                      int n) {
    gemm_k<H, false, false, true, false, false><<<gemmGrid(n), 256, 0, stream>>>(
        cur, Wsarr, nullptr, nullptr, nullptr, nullptr, nullptr, barr, 1, alt,
        nullptr, n);
    gemm_k<H, false, false, true, false, false><<<gemmGrid(n), 256, 0, stream>>>(
        alt, Wsarr + HH, nullptr, nullptr, nullptr, nullptr, nullptr, barr + H, 1,
        cur, nullptr, n);
  };

  encEdgeM(0, 2, e0in_b);
  float* h1cur = h1a; float* h1alt = h1b;
  float* h2cur = h2a; float* h2alt = h2b;
  encPlain(h1cur, h1alt, e1in_Ws, e1in_b, TF);   // h1a was zeroed
  encPlain(h2cur, h2alt, e2in_Ws, e2in_b, B);    // h2a was zeroed

  for (int step = 0; step < 2; ++step) {
    hipMemsetAsync(p01s, 0, (size_t)TF * H * 4, stream);
    pool_p01<<<400, 128, 0, stream>>>(h0h, h0l, a0l, b0, p01s);
    mean40<<<B, 128, 0, stream>>>(h1cur, p12);
    gemm_k<H, false, false, false, false, false><<<gemmGrid(TF), 256, 0, stream>>>(
        h1cur, D1, nullptr, nullptr, nullptr, nullptr, nullptr, nullptr, 0, h1d,
        nullptr, TF);
    gemm_k<H, false, false, false, false, false><<<gemmGrid(B), 256, 0, stream>>>(
        h2cur, D2, nullptr, nullptr, nullptr, nullptr, nullptr, nullptr, 0, h2d,
        nullptr, B);
    // n0 = relu(h0@A0 + (h1@D1)[assign0] + ib0)   (in-place on planes, MFMA)
    mgemm<false, true><<<MG, 256, 0, stream>>>(
        h0h, h0l, wt + (size_t)8 * 32768, nullptr, nullptr, nullptr, h1d, assign0,
        ib0, h0h, h0l, N);
    // n1 = relu(h1@A1 + mean_p01@U0 + (h2@D2)[assign1] + ib1)
    gemm_k<H, true, true, true, true, false><<<gemmGrid(TF), 256, 0, stream>>>(
        h1cur, A1, p01s, U0, rdeg1, h2d, assign1, ib1, 1, h1alt, nullptr, TF);
    // n2 = relu(h2@A2 + p12@U1 + ib2)
    gemm_k<H, true, false, true, false, false><<<gemmGrid(B), 256, 0, stream>>>(
        h2cur, A2, p12, U1, nullptr, nullptr, nullptr, ib2, 1, h2alt, nullptr, B);
    { float* tsw = h1cur; h1cur = h1alt; h1alt = tsw; }
    { float* tsw = h2cur; h2cur = h2alt; h2alt = tsw; }
    encEdgeM(4, 6, enc0_b);
    encPlain(h1cur, h1alt, enc1_Ws, enc1_b, TF);
    encPlain(h2cur, h2alt, enc2_Ws, enc2_b, B);
  }

  pool_g0<<<400, 128, 0, stream>>>(h0h, h0l, b0, g0s);
  mean40<<<B, 128, 0, stream>>>(h1cur, g1);
  head_k<<<B, 128, 0, stream>>>(g0s, rdegB, g1, h2cur, H1w, hb1, H2w, hb2, out);
}

// Round 6
// 1409.709 us; speedup vs baseline: 1.9713x; 1.0483x over previous
//
#include <hip/hip_runtime.h>

namespace {

constexpr int N   = 100000;
constexpr int E   = 600000;
constexpr int B   = 50;
constexpr int F   = 40;
constexpr int TF  = B * F;     // 2000
constexpr int D0  = 64;
constexpr int H   = 128;
constexpr int C   = 2;

typedef __attribute__((ext_vector_type(8))) __bf16 bf16x8;
typedef __attribute__((ext_vector_type(8))) unsigned short us8;
typedef __attribute__((ext_vector_type(4))) float f32x4;

__device__ __forceinline__ float asf(unsigned u) { return __uint_as_float(u); }
// round-to-nearest-even fp32 -> bf16 (returns low 16 bits)
__device__ __forceinline__ unsigned bfr(float x) {
  unsigned u = __float_as_uint(x);
  return (u + 0x7FFFu + ((u >> 16) & 1u)) >> 16;
}

// ---------------- histograms / CSR build ----------------

__global__ void hist_edges(const int* __restrict__ dst, int* __restrict__ deg) {
  int e = blockIdx.x * 256 + threadIdx.x;
  if (e < E) atomicAdd(&deg[dst[e]], 1);
}

__global__ void hist_nodes(const int* __restrict__ b0, const int* __restrict__ a0l,
                           int* __restrict__ cnt1, int* __restrict__ assign0) {
  __shared__ int lh[TF];
  int t = threadIdx.x;
  for (int j = t; j < TF; j += 256) lh[j] = 0;
  __syncthreads();
  int i = blockIdx.x * 256 + t;
  if (i < N) {
    int g = b0[i];
    int a = g * F + a0l[i];
    assign0[i] = a;
    atomicAdd(&lh[a], 1);
  }
  __syncthreads();
  for (int j = t; j < TF; j += 256) {
    int c = lh[j];
    if (c) atomicAdd(&cnt1[j], c);
  }
}

__global__ void scan1(const int* __restrict__ cnt, int* __restrict__ offs,
                      int* __restrict__ part) {
  __shared__ int lds[256];
  int t = threadIdx.x;
  int base = blockIdx.x * 1024 + t * 4;
  int v[4];
#pragma unroll
  for (int j = 0; j < 4; ++j) v[j] = (base + j < N) ? cnt[base + j] : 0;
  int s = v[0] + v[1] + v[2] + v[3];
  lds[t] = s;
  __syncthreads();
  for (int off = 1; off < 256; off <<= 1) {
    int x = (t >= off) ? lds[t - off] : 0;
    __syncthreads();
    lds[t] += x;
    __syncthreads();
  }
  int ex = lds[t] - s;
  if (t == 255) part[blockIdx.x] = lds[255];
  int run = ex;
#pragma unroll
  for (int j = 0; j < 4; ++j) {
    if (base + j < N) offs[base + j] = run;
    run += v[j];
  }
}

__global__ void scan2(const int* __restrict__ part, int* __restrict__ partEx, int nb) {
  __shared__ int lds[128];
  int t = threadIdx.x;
  int s = (t < nb) ? part[t] : 0;
  lds[t] = s;
  __syncthreads();
  for (int off = 1; off < 128; off <<= 1) {
    int x = (t >= off) ? lds[t - off] : 0;
    __syncthreads();
    lds[t] += x;
    __syncthreads();
  }
  partEx[t] = lds[t] - s;
}

__global__ void scan3(int* __restrict__ offs, const int* __restrict__ partEx,
                      const int* __restrict__ deg, float* __restrict__ rdeg,
                      const int* __restrict__ cnt1, float* __restrict__ rdeg1,
                      float* __restrict__ rdegB, int* __restrict__ assign1) {
  int i = blockIdx.x * 256 + threadIdx.x;
  if (i < N) {
    offs[i] += partEx[i >> 10];
    rdeg[i] = 1.0f / fmaxf((float)deg[i], 1.0f);
    if (i == 0) offs[N] = E;
    if (i < TF) { rdeg1[i] = 1.0f / fmaxf((float)cnt1[i], 1.0f); assign1[i] = i / F; }
    if (i < B) {
      int s = 0;
      for (int f = 0; f < F; ++f) s += cnt1[i * F + f];
      rdegB[i] = 1.0f / fmaxf((float)s, 1.0f);
    }
  }
}

__global__ void scatter_k(const int* __restrict__ src, const int* __restrict__ dst,
                          const int* __restrict__ offs, int* __restrict__ cursor,
                          int* __restrict__ srcS) {
  int e = blockIdx.x * 256 + threadIdx.x;
  if (e < E) {
    int d = dst[e];
    int pos = offs[d] + atomicAdd(&cursor[d], 1);
    srcS[pos] = src[e];
  }
}

// ---- weight conversion: fp32 [k][c] -> split-bf16, slice-major, col-permuted ----
// per H*H matrix (32768 shorts): hi [ks][c_s][32] at 0, lo at +16384.
// storage slot c_s = (c&7)*16 + (c>>3) holds output column c -> mgemm (nf,lm)
// fragment covers cols lm*8+nf (lane-contiguous epilogue).
struct WPtrs { const float* w[9]; };
__global__ void conv_w(WPtrs wp, unsigned short* __restrict__ wt) {
  int i = blockIdx.x >> 6;                         // matrix index
  int e = (blockIdx.x & 63) * 256 + threadIdx.x;   // 0..16383
  int k = e >> 7, c = e & 127;
  float x = wp.w[i][e];
  unsigned h = bfr(x);
  unsigned l = bfr(x - asf(h << 16));
  int cs = (c & 7) * 16 + (c >> 3);
  size_t o = (size_t)i * 32768 + (k >> 5) * 4096 + cs * 32 + (k & 31);
  wt[o] = (unsigned short)h;
  wt[o + 16384] = (unsigned short)l;
}

// Wp: fp32 [64][128] -> hi (2 slices * 4096) + lo at +8192
__global__ void conv_wp(const float* __restrict__ w, unsigned short* __restrict__ wt) {
  int e = blockIdx.x * 256 + threadIdx.x;  // 0..8191
  int k = e >> 7, c = e & 127;
  float x = w[e];
  unsigned h = bfr(x);
  unsigned l = bfr(x - asf(h << 16));
  int cs = (c & 7) * 16 + (c >> 3);
  size_t o = (size_t)(k >> 5) * 4096 + cs * 32 + (k & 31);
  wt[o] = (unsigned short)h;
  wt[o + 8192] = (unsigned short)l;
}

// x0 fp32 [N][64] -> interleaved rows [hi64 | lo64] (stride 128 shorts)
__global__ void x0split(const float* __restrict__ x0, unsigned short* __restrict__ xs) {
  int i = blockIdx.x * 256 + threadIdx.x;  // elem index
  if (i >= N * D0) return;
  int row = i >> 6, c = i & 63;
  float x = x0[i];
  unsigned h = bfr(x);
  unsigned l = bfr(x - asf(h << 16));
  xs[(size_t)row * 128 + c] = (unsigned short)h;
  xs[(size_t)row * 128 + 64 + c] = (unsigned short)l;
}

// ---------------- edge aggregation (interleaved hi|lo rows, 512B) ----------------
// ONE uint2 load per lane per edge: lanes 0-31 accumulate hi-cols 4l..4l+3,
// lanes 32-63 accumulate lo-cols of the same; shfl_xor(32) merges.
__global__ void agg_k(const unsigned short* __restrict__ Act,
                      const int* __restrict__ offs, const int* __restrict__ srcS,
                      const float* __restrict__ rdeg, unsigned short* __restrict__ Out) {
  int wid = blockIdx.x * 4 + (threadIdx.x >> 6);
  int lane = threadIdx.x & 63;
  if (wid >= N) return;
  int o0 = offs[wid], o1 = offs[wid + 1];
  float s0 = 0.f, s1 = 0.f, s2 = 0.f, s3 = 0.f;
  int e = o0;
  for (; e + 3 < o1; e += 4) {
    uint2 v0 = *(const uint2*)(Act + (size_t)srcS[e] * 256 + lane * 4);
    uint2 v1 = *(const uint2*)(Act + (size_t)srcS[e + 1] * 256 + lane * 4);
    uint2 v2 = *(const uint2*)(Act + (size_t)srcS[e + 2] * 256 + lane * 4);
    uint2 v3 = *(const uint2*)(Act + (size_t)srcS[e + 3] * 256 + lane * 4);
    s0 += asf(v0.x << 16) + asf(v1.x << 16) + asf(v2.x << 16) + asf(v3.x << 16);
    s1 += asf(v0.x & 0xFFFF0000u) + asf(v1.x & 0xFFFF0000u) +
          asf(v2.x & 0xFFFF0000u) + asf(v3.x & 0xFFFF0000u);
    s2 += asf(v0.y << 16) + asf(v1.y << 16) + asf(v2.y << 16) + asf(v3.y << 16);
    s3 += asf(v0.y & 0xFFFF0000u) + asf(v1.y & 0xFFFF0000u) +
          asf(v2.y & 0xFFFF0000u) + asf(v3.y & 0xFFFF0000u);
  }
  for (; e < o1; ++e) {
    uint2 v0 = *(const uint2*)(Act + (size_t)srcS[e] * 256 + lane * 4);
    s0 += asf(v0.x << 16);
    s1 += asf(v0.x & 0xFFFF0000u);
    s2 += asf(v0.y << 16);
    s3 += asf(v0.y & 0xFFFF0000u);
  }
  float sc = rdeg[wid];
  float v0 = (s0 + __shfl_xor(s0, 32)) * sc;
  float v1 = (s1 + __shfl_xor(s1, 32)) * sc;
  float v2 = (s2 + __shfl_xor(s2, 32)) * sc;
  float v3 = (s3 + __shfl_xor(s3, 32)) * sc;
  unsigned h0 = bfr(v0), h1 = bfr(v1), h2 = bfr(v2), h3 = bfr(v3);
  unsigned w0, w1;
  if (lane < 32) {
    w0 = h0 | (h1 << 16);
    w1 = h2 | (h3 << 16);
  } else {
    unsigned l0 = bfr(v0 - asf(h0 << 16)), l1 = bfr(v1 - asf(h1 << 16));
    unsigned l2 = bfr(v2 - asf(h2 << 16)), l3 = bfr(v3 - asf(h3 << 16));
    w0 = l0 | (l1 << 16);
    w1 = l2 | (l3 << 16);
  }
  unsigned short* po = Out + (size_t)wid * 256 + (lane & 31) * 4 + (lane >= 32 ? 128 : 0);
  *(uint2*)po = make_uint2(w0, w1);
}

// ---------------- split-bf16 MFMA GEMM, LDS-staged weights ----------------
// out = relu( A@W1 [+ Agg@W2] [+ Gt[Gidx]] + bias )
// activations interleaved [hi[KD] | lo[KD]] rows; output rows stride 256.
template <int KD, bool AGG, bool GATH>
__global__ __launch_bounds__(256, 3)
void mgemm(const unsigned short* __restrict__ Ai, const unsigned short* __restrict__ W1,
           const unsigned short* __restrict__ Bi, const unsigned short* __restrict__ W2,
           const float* __restrict__ Gt, const int* __restrict__ Gidx,
           const float* __restrict__ bias, unsigned short* __restrict__ Oi, int n) {
  __shared__ unsigned short wlds[2][2][4096];  // [buf][hi/lo][slice]
  constexpr int KS = KD / 32;        // k-slices per matrix
  constexpr int NS = (AGG ? 2 : 1) * KS;
  constexpr int KLO = KD * 128;      // lo-plane offset inside weight matrix
  constexpr int ARS = 2 * KD;        // activation row stride (shorts)
  const int t = threadIdx.x, wv = t >> 6, ln = t & 63;
  const int row0 = blockIdx.x * 128 + wv * 32;
  const int lm = ln & 15, kg = ln >> 4;
  int ar0 = row0 + lm, ar1 = row0 + 16 + lm;
  if (ar0 >= n) ar0 = 0;
  if (ar1 >= n) ar1 = 0;
  const size_t a0off = (size_t)ar0 * ARS, a1off = (size_t)ar1 * ARS;

  f32x4 acc[2][8];
#pragma unroll
  for (int i = 0; i < 2; ++i)
#pragma unroll
    for (int j = 0; j < 8; ++j) acc[i][j] = (f32x4){0.f, 0.f, 0.f, 0.f};

  uint4 sA, sB, sC, sD;
  bf16x8 a0h[2], a0l[2], a1h[2], a1l[2];

  auto ldst = [&](int s) {
    const unsigned short* W = (AGG && s >= KS) ? W2 : W1;
    const unsigned short* ph = W + (s & (KS - 1)) * 4096;
    sA = *(const uint4*)(ph + t * 8);
    sB = *(const uint4*)(ph + 2048 + t * 8);
    sC = *(const uint4*)(ph + KLO + t * 8);
    sD = *(const uint4*)(ph + KLO + 2048 + t * 8);
  };
  auto wrst = [&](int buf) {
    *(uint4*)&wlds[buf][0][t * 8] = sA;
    *(uint4*)&wlds[buf][0][2048 + t * 8] = sB;
    *(uint4*)&wlds[buf][1][t * 8] = sC;
    *(uint4*)&wlds[buf][1][2048 + t * 8] = sD;
  };
  auto loadA = [&](int s, int w) {
    const unsigned short* X = (AGG && s >= KS) ? Bi : Ai;
    int kk = (s & (KS - 1)) * 32 + kg * 8;
    a0h[w] = *(const bf16x8*)(X + a0off + kk);
    a0l[w] = *(const bf16x8*)(X + a0off + KD + kk);
    a1h[w] = *(const bf16x8*)(X + a1off + kk);
    a1l[w] = *(const bf16x8*)(X + a1off + KD + kk);
  };

  ldst(0); wrst(0); loadA(0, 0);
  __syncthreads();

#pragma unroll
  for (int s = 0; s < NS; ++s) {
    const int buf = s & 1;
    if (s + 1 < NS) { ldst(s + 1); loadA(s + 1, buf ^ 1); }
#pragma unroll
    for (int nf = 0; nf < 8; ++nf) {
      const int wo = (nf * 16 + lm) * 32 + kg * 8;
      bf16x8 wh = *(const bf16x8*)&wlds[buf][0][wo];
      bf16x8 wl = *(const bf16x8*)&wlds[buf][1][wo];
      acc[0][nf] = __builtin_amdgcn_mfma_f32_16x16x32_bf16(a0h[buf], wh, acc[0][nf], 0, 0, 0);
      acc[0][nf] = __builtin_amdgcn_mfma_f32_16x16x32_bf16(a0h[buf], wl, acc[0][nf], 0, 0, 0);
      acc[0][nf] = __builtin_amdgcn_mfma_f32_16x16x32_bf16(a0l[buf], wh, acc[0][nf], 0, 0, 0);
      acc[1][nf] = __builtin_amdgcn_mfma_f32_16x16x32_bf16(a1h[buf], wh, acc[1][nf], 0, 0, 0);
      acc[1][nf] = __builtin_amdgcn_mfma_f32_16x16x32_bf16(a1h[buf], wl, acc[1][nf], 0, 0, 0);
      acc[1][nf] = __builtin_amdgcn_mfma_f32_16x16x32_bf16(a1l[buf], wh, acc[1][nf], 0, 0, 0);
    }
    if (s + 1 < NS) wrst(buf ^ 1);
    __syncthreads();
  }

  float4 bq0 = *(const float4*)&bias[lm * 8];
  float4 bq1 = *(const float4*)&bias[lm * 8 + 4];
  float bsv[8] = {bq0.x, bq0.y, bq0.z, bq0.w, bq1.x, bq1.y, bq1.z, bq1.w};
#pragma unroll
  for (int mf = 0; mf < 2; ++mf)
#pragma unroll
    for (int rr = 0; rr < 4; ++rr) {
      int row = row0 + mf * 16 + kg * 4 + rr;  // D: row=(lane>>4)*4+reg, col=lane&15
      if (row >= n) continue;
      float gvv[8];
      if (GATH) {
        const float* grow = Gt + (size_t)Gidx[row] * H + lm * 8;
        float4 g0 = *(const float4*)grow;
        float4 g1 = *(const float4*)(grow + 4);
        gvv[0] = g0.x; gvv[1] = g0.y; gvv[2] = g0.z; gvv[3] = g0.w;
        gvv[4] = g1.x; gvv[5] = g1.y; gvv[6] = g1.z; gvv[7] = g1.w;
      }
      us8 hv, lv;
#pragma unroll
      for (int nf = 0; nf < 8; ++nf) {   // actual col = lm*8 + nf
        float v = acc[mf][nf][rr] + bsv[nf];
        if (GATH) v += gvv[nf];
        v = fmaxf(v, 0.f);
        unsigned h = bfr(v);
        hv[nf] = (unsigned short)h;
        lv[nf] = (unsigned short)bfr(v - asf(h << 16));
      }
      *(us8*)(Oi + (size_t)row * 256 + lm * 8) = hv;
      *(us8*)(Oi + (size_t)row * 256 + 128 + lm * 8) = lv;
    }
}

// ---------------- generic fused fp32 GEMM (small layers) ----------------
template <int K, bool AGG, bool GATH, bool RELU, bool SCALE>
__global__ __launch_bounds__(256)
void gemm_k(const float* __restrict__ A, const float* __restrict__ W1,
            const float* __restrict__ Agg, const float* __restrict__ W2,
            const float* __restrict__ ascale,
            const float* __restrict__ Gt, const int* __restrict__ Gidx,
            const float* __restrict__ bias, int hasBias,
            float* __restrict__ out, int n) {
  constexpr int BM = 128, KC = 16;
  __shared__ float As[KC][BM + 4];
  __shared__ float Ws[KC][H + 4];
  const int t = threadIdx.x;
  const int tx = t & 15, ty = t >> 4;
  const int row0 = blockIdx.x * BM;
  float acc[8][8];
#pragma unroll
  for (int r = 0; r < 8; ++r)
#pragma unroll
    for (int c = 0; c < 8; ++c) acc[r][c] = 0.f;

  const int sr = t >> 1;
  const int sk = (t & 1) * 8;
  const int wk = t >> 4;
  const int wc = (t & 15) * 8;

  for (int pass = 0; pass < (AGG ? 2 : 1); ++pass) {
    const float* Ain = (AGG && pass) ? Agg : A;
    const float* Win = (AGG && pass) ? W2 : W1;
    for (int k0 = 0; k0 < K; k0 += KC) {
      float4 a0 = make_float4(0, 0, 0, 0), a1 = make_float4(0, 0, 0, 0);
      int r = row0 + sr;
      if (r < n) {
        const float* ap = Ain + (size_t)r * K + k0 + sk;
        a0 = *(const float4*)ap;
        a1 = *(const float4*)(ap + 4);
        if (AGG && SCALE && pass) {
          float sc = ascale[r];
          a0.x *= sc; a0.y *= sc; a0.z *= sc; a0.w *= sc;
          a1.x *= sc; a1.y *= sc; a1.z *= sc; a1.w *= sc;
        }
      }
      const float* wp = Win + (size_t)(k0 + wk) * H + wc;
      float4 w0 = *(const float4*)wp;
      float4 w1 = *(const float4*)(wp + 4);
      __syncthreads();
      As[sk + 0][sr] = a0.x; As[sk + 1][sr] = a0.y;
      As[sk + 2][sr] = a0.z; As[sk + 3][sr] = a0.w;
      As[sk + 4][sr] = a1.x; As[sk + 5][sr] = a1.y;
      As[sk + 6][sr] = a1.z; As[sk + 7][sr] = a1.w;
      *(float4*)&Ws[wk][wc] = w0;
      *(float4*)&Ws[wk][wc + 4] = w1;
      __syncthreads();
#pragma unroll
      for (int k = 0; k < KC; ++k) {
        float4 av0 = *(const float4*)&As[k][ty * 8];
        float4 av1 = *(const float4*)&As[k][ty * 8 + 4];
        float4 bv0 = *(const float4*)&Ws[k][tx * 8];
        float4 bv1 = *(const float4*)&Ws[k][tx * 8 + 4];
        float a_[8] = {av0.x, av0.y, av0.z, av0.w, av1.x, av1.y, av1.z, av1.w};
        float b_[8] = {bv0.x, bv0.y, bv0.z, bv0.w, bv1.x, bv1.y, bv1.z, bv1.w};
#pragma unroll
        for (int rr = 0; rr < 8; ++rr)
#pragma unroll
          for (int cc = 0; cc < 8; ++cc) acc[rr][cc] += a_[rr] * b_[cc];
      }
    }
  }

#pragma unroll
  for (int rr = 0; rr < 8; ++rr) {
    int row = row0 + ty * 8 + rr;
    if (row >= n) continue;
    const float* grow = nullptr;
    if (GATH) grow = Gt + (size_t)Gidx[row] * H;
    float v[8];
#pragma unroll
    for (int cc = 0; cc < 8; ++cc) {
      int col = tx * 8 + cc;
      float x = acc[rr][cc];
      if (hasBias) x += bias[col];
      if (GATH) x += grow[col];
      if (RELU) x = fmaxf(x, 0.f);
      v[cc] = x;
    }
    float* op = out + (size_t)row * H + tx * 8;
    *(float4*)op = make_float4(v[0], v[1], v[2], v[3]);
    *(float4*)(op + 4) = make_float4(v[4], v[5], v[6], v[7]);
  }
}

// ---------------- pooling (interleaved rows) ----------------
__global__ void pool_p01(const unsigned short* __restrict__ Act,
                         const int* __restrict__ a0l, const int* __restrict__ b0,
                         float* __restrict__ p01s) {
  __shared__ float acc[F][H];
  int t = threadIdx.x;  // 128
#pragma unroll
  for (int f = 0; f < F; ++f) acc[f][t] = 0.f;
  int rowbase = blockIdx.x * 250;
  for (int i = 0; i < 250; ++i) {
    size_t r = (size_t)(rowbase + i) * 256 + t;
    acc[a0l[rowbase + i]][t] += asf((unsigned)Act[r] << 16) + asf((unsigned)Act[r + 128] << 16);
  }
  int g = b0[rowbase];
#pragma unroll
  for (int f = 0; f < F; ++f)
    atomicAdd(&p01s[((size_t)(g * F + f)) * H + t], acc[f][t]);
}

__global__ void pool_g0(const unsigned short* __restrict__ Act,
                        const int* __restrict__ b0, float* __restrict__ g0s) {
  int t = threadIdx.x;
  int rowbase = blockIdx.x * 250;
  float a = 0.f;
  for (int i = 0; i < 250; ++i) {
    size_t r = (size_t)(rowbase + i) * 256 + t;
    a += asf((unsigned)Act[r] << 16) + asf((unsigned)Act[r + 128] << 16);
  }
  atomicAdd(&g0s[(size_t)b0[rowbase] * H + t], a);
}

__global__ void mean40(const float* __restrict__ hin, float* __restrict__ outp) {
  int t = threadIdx.x, g = blockIdx.x;
  float a = 0.f;
  for (int i = 0; i < F; ++i) a += hin[(size_t)(g * F + i) * H + t];
  outp[(size_t)g * H + t] = a * (1.0f / F);
}

// ---------------- head MLP ----------------
__global__ void head_k(const float* __restrict__ g0s, const float* __restrict__ rdegB,
                       const float* __restrict__ g1, const float* __restrict__ h2,
                       const float* __restrict__ W1h, const float* __restrict__ b1h,
                       const float* __restrict__ W2h, const float* __restrict__ b2h,
                       float* __restrict__ out) {
  __shared__ float gv[3 * H];
  __shared__ float z[H];
  int b = blockIdx.x, t = threadIdx.x;
  gv[t] = g0s[(size_t)b * H + t] * rdegB[b];
  gv[H + t] = g1[(size_t)b * H + t];
  gv[2 * H + t] = h2[(size_t)b * H + t];
  __syncthreads();
  float s = b1h[t];
  for (int k = 0; k < 3 * H; ++k) s += gv[k] * W1h[k * H + t];
  z[t] = fmaxf(s, 0.f);
  __syncthreads();
  if (t < C) {
    float o = b2h[t];
    for (int k = 0; k < H; ++k) o += z[k] * W2h[k * C + t];
    out[b * C + t] = o;
  }
}

}  // namespace

extern "C" void kernel_launch(void* const* d_in, const int* in_sizes, int n_in,
                              void* d_out, int out_size, void* d_ws, size_t ws_size,
                              hipStream_t stream) {
  (void)in_sizes; (void)n_in; (void)out_size; (void)ws_size;
  const float* x0   = (const float*)d_in[0];
  const int*   ei   = (const int*)d_in[1];
  const int*   src  = ei;
  const int*   dst  = ei + E;
  const int*   b0   = (const int*)d_in[2];
  const int*   a0l  = (const int*)d_in[3];
  const float* Wp   = (const float*)d_in[4];
  const float* bp   = (const float*)d_in[5];
  const float* e0in_Ws = (const float*)d_in[6];
  const float* e0in_Wn = (const float*)d_in[7];
  const float* e0in_b  = (const float*)d_in[8];
  const float* enc0_Ws = (const float*)d_in[9];
  const float* enc0_Wn = (const float*)d_in[10];
  const float* enc0_b  = (const float*)d_in[11];
  const float* e1in_Ws = (const float*)d_in[12];
  const float* e1in_b  = (const float*)d_in[13];
  const float* e2in_Ws = (const float*)d_in[14];
  const float* e2in_b  = (const float*)d_in[15];
  const float* enc1_Ws = (const float*)d_in[16];
  const float* enc1_b  = (const float*)d_in[17];
  const float* enc2_Ws = (const float*)d_in[18];
  const float* enc2_b  = (const float*)d_in[19];
  const float* A0 = (const float*)d_in[20];
  const float* A1 = (const float*)d_in[21];
  const float* A2 = (const float*)d_in[22];
  const float* U0 = (const float*)d_in[23];
  const float* U1 = (const float*)d_in[24];
  const float* D1 = (const float*)d_in[25];
  const float* D2 = (const float*)d_in[26];
  const float* ib0 = (const float*)d_in[27];
  const float* ib1 = (const float*)d_in[28];
  const float* ib2 = (const float*)d_in[29];
  const float* H1w = (const float*)d_in[30];
  const float* hb1 = (const float*)d_in[31];
  const float* H2w = (const float*)d_in[32];
  const float* hb2 = (const float*)d_in[33];
  float* out = (float*)d_out;

  // ---- workspace carve ----
  char* p = (char*)d_ws;
  auto carve = [&](size_t bytes) {
    char* r = p;
    p += (bytes + 255) & ~(size_t)255;
    return r;
  };
  char* z0 = p;  // zeroed-every-call region
  int*   deg    = (int*)carve((size_t)N * 4);
  int*   cursor = (int*)carve((size_t)N * 4);
  int*   cnt1   = (int*)carve((size_t)TF * 4);
  float* h1a    = (float*)carve((size_t)TF * H * 4);
  float* h2a    = (float*)carve((size_t)B * H * 4);
  float* g0s    = (float*)carve((size_t)B * H * 4);
  size_t zbytes = (size_t)(p - z0);
  unsigned short* h0i  = (unsigned short*)carve((size_t)N * 256 * 2);
  unsigned short* aggi = (unsigned short*)carve((size_t)N * 256 * 2);
  float* h1b  = (float*)carve((size_t)TF * H * 4);
  float* h1d  = (float*)carve((size_t)TF * H * 4);
  float* p01s = (float*)carve((size_t)TF * H * 4);
  float* h2b  = (float*)carve((size_t)B * H * 4);
  float* h2d  = (float*)carve((size_t)B * H * 4);
  float* p12  = (float*)carve((size_t)B * H * 4);
  float* g1   = (float*)carve((size_t)B * H * 4);
  float* rdeg = (float*)carve((size_t)N * 4);
  float* rdeg1 = (float*)carve((size_t)TF * 4);
  float* rdegB = (float*)carve(64 * 4);
  int* offs    = (int*)carve((size_t)(N + 64) * 4);
  int* srcS    = (int*)carve((size_t)E * 4);
  int* part    = (int*)carve(128 * 4);
  int* partEx  = (int*)carve(128 * 4);
  int* assign0 = (int*)carve((size_t)N * 4);
  int* assign1 = (int*)carve((size_t)TF * 4);
  unsigned short* wt  = (unsigned short*)carve((size_t)9 * 32768 * 2);
  unsigned short* wt9 = (unsigned short*)carve((size_t)16384 * 2);
  unsigned short* xs  = aggi;  // alias: x0-split used only before first agg_k

  auto gemmGrid = [](int n) { return (n + 127) / 128; };
  const int HH = H * H;
  const int MG = (N + 127) / 128;  // 782

  // ---- CSR + histograms + weight/x0 split ----
  hipMemsetAsync(z0, 0, zbytes, stream);
  hist_edges<<<(E + 255) / 256, 256, 0, stream>>>(dst, deg);
  hist_nodes<<<(N + 255) / 256, 256, 0, stream>>>(b0, a0l, cnt1, assign0);
  const int nb1 = (N + 1023) / 1024;
  scan1<<<nb1, 256, 0, stream>>>(deg, offs, part);
  scan2<<<1, 128, 0, stream>>>(part, partEx, nb1);
  scan3<<<(N + 255) / 256, 256, 0, stream>>>(offs, partEx, deg, rdeg, cnt1, rdeg1,
                                             rdegB, assign1);
  scatter_k<<<(E + 255) / 256, 256, 0, stream>>>(src, dst, offs, cursor, srcS);
  {
    WPtrs wp;
    wp.w[0] = e0in_Ws;      wp.w[1] = e0in_Ws + HH;
    wp.w[2] = e0in_Wn;      wp.w[3] = e0in_Wn + HH;
    wp.w[4] = enc0_Ws;      wp.w[5] = enc0_Ws + HH;
    wp.w[6] = enc0_Wn;      wp.w[7] = enc0_Wn + HH;
    wp.w[8] = A0;
    conv_w<<<9 * 64, 256, 0, stream>>>(wp, wt);
  }
  conv_wp<<<32, 256, 0, stream>>>(Wp, wt9);
  x0split<<<(N * D0 + 255) / 256, 256, 0, stream>>>(x0, xs);

  // ---- input projection (MFMA, K=64) ----
  mgemm<64, false, false><<<MG, 256, 0, stream>>>(
      xs, wt9, nullptr, nullptr, nullptr, nullptr, bp, h0i, N);

  auto encEdgeM = [&](int wsIdx, int wnIdx, const float* barr) {
    for (int l = 0; l < 2; ++l) {
      agg_k<<<N / 4, 256, 0, stream>>>(h0i, offs, srcS, rdeg, aggi);
      mgemm<128, true, false><<<MG, 256, 0, stream>>>(
          h0i, wt + (size_t)(wsIdx + l) * 32768, aggi,
          wt + (size_t)(wnIdx + l) * 32768, nullptr, nullptr, barr + l * H, h0i, N);
    }
  };
  auto encPlain = [&](float* cur, float* alt, const float* Wsarr, const float* barr,
                      int n) {
    gemm_k<H, false, false, true, false><<<gemmGrid(n), 256, 0, stream>>>(
        cur, Wsarr, nullptr, nullptr, nullptr, nullptr, nullptr, barr, 1, alt, n);
    gemm_k<H, false, false, true, false><<<gemmGrid(n), 256, 0, stream>>>(
        alt, Wsarr + HH, nullptr, nullptr, nullptr, nullptr, nullptr, barr + H, 1,
        cur, n);
  };

  encEdgeM(0, 2, e0in_b);
  float* h1cur = h1a; float* h1alt = h1b;
  float* h2cur = h2a; float* h2alt = h2b;
  encPlain(h1cur, h1alt, e1in_Ws, e1in_b, TF);   // h1a was zeroed
  encPlain(h2cur, h2alt, e2in_Ws, e2in_b, B);    // h2a was zeroed

  for (int step = 0; step < 2; ++step) {
    hipMemsetAsync(p01s, 0, (size_t)TF * H * 4, stream);
    pool_p01<<<400, 128, 0, stream>>>(h0i, a0l, b0, p01s);
    mean40<<<B, 128, 0, stream>>>(h1cur, p12);
    gemm_k<H, false, false, false, false><<<gemmGrid(TF), 256, 0, stream>>>(
        h1cur, D1, nullptr, nullptr, nullptr, nullptr, nullptr, nullptr, 0, h1d, TF);
    gemm_k<H, false, false, false, false><<<gemmGrid(B), 256, 0, stream>>>(
        h2cur, D2, nullptr, nullptr, nullptr, nullptr, nullptr, nullptr, 0, h2d, B);
    // n0 = relu(h0@A0 + (h1@D1)[assign0] + ib0)   (in-place, MFMA)
    mgemm<128, false, true><<<MG, 256, 0, stream>>>(
        h0i, wt + (size_t)8 * 32768, nullptr, nullptr, h1d, assign0, ib0, h0i, N);
    // n1 = relu(h1@A1 + mean_p01@U0 + (h2@D2)[assign1] + ib1)
    gemm_k<H, true, true, true, true><<<gemmGrid(TF), 256, 0, stream>>>(
        h1cur, A1, p01s, U0, rdeg1, h2d, assign1, ib1, 1, h1alt, TF);
    // n2 = relu(h2@A2 + p12@U1 + ib2)
    gemm_k<H, true, false, true, false><<<gemmGrid(B), 256, 0, stream>>>(
        h2cur, A2, p12, U1, nullptr, nullptr, nullptr, ib2, 1, h2alt, B);
    { float* tsw = h1cur; h1cur = h1alt; h1alt = tsw; }
    { float* tsw = h2cur; h2cur = h2alt; h2alt = tsw; }
    encEdgeM(4, 6, enc0_b);
    encPlain(h1cur, h1alt, enc1_Ws, enc1_b, TF);
    encPlain(h2cur, h2alt, enc2_Ws, enc2_b, B);
  }

  pool_g0<<<400, 128, 0, stream>>>(h0i, b0, g0s);
  mean40<<<B, 128, 0, stream>>>(h1cur, g1);
  head_k<<<B, 128, 0, stream>>>(g0s, rdegB, g1, h2cur, H1w, hb1, H2w, hb2, out);
}

// Round 7
// 1032.505 us; speedup vs baseline: 2.6915x; 1.3653x over previous
//
#include <hip/hip_runtime.h>

namespace {

constexpr int N   = 100000;
constexpr int E   = 600000;
constexpr int B   = 50;
constexpr int F   = 40;
constexpr int TF  = B * F;     // 2000
constexpr int D0  = 64;
constexpr int H   = 128;
constexpr int C   = 2;

typedef __attribute__((ext_vector_type(8))) __bf16 bf16x8;
typedef __attribute__((ext_vector_type(8))) unsigned short us8;
typedef __attribute__((ext_vector_type(4))) float f32x4;

__device__ __forceinline__ float asf(unsigned u) { return __uint_as_float(u); }
// round-to-nearest-even fp32 -> bf16 (returns low 16 bits)
__device__ __forceinline__ unsigned bfr(float x) {
  unsigned u = __float_as_uint(x);
  return (u + 0x7FFFu + ((u >> 16) & 1u)) >> 16;
}

// ---------------- histograms / CSR build ----------------

__global__ void hist_edges(const int* __restrict__ dst, int* __restrict__ deg) {
  int e = blockIdx.x * 256 + threadIdx.x;
  if (e < E) atomicAdd(&deg[dst[e]], 1);
}

__global__ void hist_nodes(const int* __restrict__ b0, const int* __restrict__ a0l,
                           int* __restrict__ cnt1, int* __restrict__ assign0) {
  __shared__ int lh[TF];
  int t = threadIdx.x;
  for (int j = t; j < TF; j += 256) lh[j] = 0;
  __syncthreads();
  int i = blockIdx.x * 256 + t;
  if (i < N) {
    int g = b0[i];
    int a = g * F + a0l[i];
    assign0[i] = a;
    atomicAdd(&lh[a], 1);
  }
  __syncthreads();
  for (int j = t; j < TF; j += 256) {
    int c = lh[j];
    if (c) atomicAdd(&cnt1[j], c);
  }
}

__global__ void scan1(const int* __restrict__ cnt, int* __restrict__ offs,
                      int* __restrict__ part) {
  __shared__ int lds[256];
  int t = threadIdx.x;
  int base = blockIdx.x * 1024 + t * 4;
  int v[4];
#pragma unroll
  for (int j = 0; j < 4; ++j) v[j] = (base + j < N) ? cnt[base + j] : 0;
  int s = v[0] + v[1] + v[2] + v[3];
  lds[t] = s;
  __syncthreads();
  for (int off = 1; off < 256; off <<= 1) {
    int x = (t >= off) ? lds[t - off] : 0;
    __syncthreads();
    lds[t] += x;
    __syncthreads();
  }
  int ex = lds[t] - s;
  if (t == 255) part[blockIdx.x] = lds[255];
  int run = ex;
#pragma unroll
  for (int j = 0; j < 4; ++j) {
    if (base + j < N) offs[base + j] = run;
    run += v[j];
  }
}

__global__ void scan2(const int* __restrict__ part, int* __restrict__ partEx, int nb) {
  __shared__ int lds[128];
  int t = threadIdx.x;
  int s = (t < nb) ? part[t] : 0;
  lds[t] = s;
  __syncthreads();
  for (int off = 1; off < 128; off <<= 1) {
    int x = (t >= off) ? lds[t - off] : 0;
    __syncthreads();
    lds[t] += x;
    __syncthreads();
  }
  partEx[t] = lds[t] - s;
}

__global__ void scan3(int* __restrict__ offs, const int* __restrict__ partEx,
                      const int* __restrict__ deg, float* __restrict__ rdeg,
                      const int* __restrict__ cnt1, float* __restrict__ rdeg1,
                      float* __restrict__ rdegB, int* __restrict__ assign1) {
  int i = blockIdx.x * 256 + threadIdx.x;
  if (i < N) {
    offs[i] += partEx[i >> 10];
    rdeg[i] = 1.0f / fmaxf((float)deg[i], 1.0f);
    if (i == 0) offs[N] = E;
    if (i < TF) { rdeg1[i] = 1.0f / fmaxf((float)cnt1[i], 1.0f); assign1[i] = i / F; }
    if (i < B) {
      int s = 0;
      for (int f = 0; f < F; ++f) s += cnt1[i * F + f];
      rdegB[i] = 1.0f / fmaxf((float)s, 1.0f);
    }
  }
}

__global__ void scatter_k(const int* __restrict__ src, const int* __restrict__ dst,
                          const int* __restrict__ offs, int* __restrict__ cursor,
                          int* __restrict__ srcS) {
  int e = blockIdx.x * 256 + threadIdx.x;
  if (e < E) {
    int d = dst[e];
    int pos = offs[d] + atomicAdd(&cursor[d], 1);
    srcS[pos] = src[e];
  }
}

// ---- weight conversion: fp32 [k][c] -> split-bf16, slice-major, col-permuted ----
struct WPtrs { const float* w[9]; };
__global__ void conv_w(WPtrs wp, unsigned short* __restrict__ wt) {
  int i = blockIdx.x >> 6;                         // matrix index
  int e = (blockIdx.x & 63) * 256 + threadIdx.x;   // 0..16383
  int k = e >> 7, c = e & 127;
  float x = wp.w[i][e];
  unsigned h = bfr(x);
  unsigned l = bfr(x - asf(h << 16));
  int cs = (c & 7) * 16 + (c >> 3);
  size_t o = (size_t)i * 32768 + (k >> 5) * 4096 + cs * 32 + (k & 31);
  wt[o] = (unsigned short)h;
  wt[o + 16384] = (unsigned short)l;
}

// Wp: fp32 [64][128] -> hi (2 slices * 4096) + lo at +8192
__global__ void conv_wp(const float* __restrict__ w, unsigned short* __restrict__ wt) {
  int e = blockIdx.x * 256 + threadIdx.x;  // 0..8191
  int k = e >> 7, c = e & 127;
  float x = w[e];
  unsigned h = bfr(x);
  unsigned l = bfr(x - asf(h << 16));
  int cs = (c & 7) * 16 + (c >> 3);
  size_t o = (size_t)(k >> 5) * 4096 + cs * 32 + (k & 31);
  wt[o] = (unsigned short)h;
  wt[o + 8192] = (unsigned short)l;
}

// x0 fp32 [N][64] -> interleaved rows [hi64 | lo64] (stride 128 shorts)
__global__ void x0split(const float* __restrict__ x0, unsigned short* __restrict__ xs) {
  int i = blockIdx.x * 256 + threadIdx.x;  // elem index
  if (i >= N * D0) return;
  int row = i >> 6, c = i & 63;
  float x = x0[i];
  unsigned h = bfr(x);
  unsigned l = bfr(x - asf(h << 16));
  xs[(size_t)row * 128 + c] = (unsigned short)h;
  xs[(size_t)row * 128 + 64 + c] = (unsigned short)l;
}

// ---------------- edge aggregation (interleaved hi|lo rows, 512B) ----------------
__global__ void agg_k(const unsigned short* __restrict__ Act,
                      const int* __restrict__ offs, const int* __restrict__ srcS,
                      const float* __restrict__ rdeg, unsigned short* __restrict__ Out) {
  int wid = blockIdx.x * 4 + (threadIdx.x >> 6);
  int lane = threadIdx.x & 63;
  if (wid >= N) return;
  int o0 = offs[wid], o1 = offs[wid + 1];
  float s0 = 0.f, s1 = 0.f, s2 = 0.f, s3 = 0.f;
  int e = o0;
  for (; e + 3 < o1; e += 4) {
    uint2 v0 = *(const uint2*)(Act + (size_t)srcS[e] * 256 + lane * 4);
    uint2 v1 = *(const uint2*)(Act + (size_t)srcS[e + 1] * 256 + lane * 4);
    uint2 v2 = *(const uint2*)(Act + (size_t)srcS[e + 2] * 256 + lane * 4);
    uint2 v3 = *(const uint2*)(Act + (size_t)srcS[e + 3] * 256 + lane * 4);
    s0 += asf(v0.x << 16) + asf(v1.x << 16) + asf(v2.x << 16) + asf(v3.x << 16);
    s1 += asf(v0.x & 0xFFFF0000u) + asf(v1.x & 0xFFFF0000u) +
          asf(v2.x & 0xFFFF0000u) + asf(v3.x & 0xFFFF0000u);
    s2 += asf(v0.y << 16) + asf(v1.y << 16) + asf(v2.y << 16) + asf(v3.y << 16);
    s3 += asf(v0.y & 0xFFFF0000u) + asf(v1.y & 0xFFFF0000u) +
          asf(v2.y & 0xFFFF0000u) + asf(v3.y & 0xFFFF0000u);
  }
  for (; e < o1; ++e) {
    uint2 v0 = *(const uint2*)(Act + (size_t)srcS[e] * 256 + lane * 4);
    s0 += asf(v0.x << 16);
    s1 += asf(v0.x & 0xFFFF0000u);
    s2 += asf(v0.y << 16);
    s3 += asf(v0.y & 0xFFFF0000u);
  }
  float sc = rdeg[wid];
  float v0 = (s0 + __shfl_xor(s0, 32)) * sc;
  float v1 = (s1 + __shfl_xor(s1, 32)) * sc;
  float v2 = (s2 + __shfl_xor(s2, 32)) * sc;
  float v3 = (s3 + __shfl_xor(s3, 32)) * sc;
  unsigned h0 = bfr(v0), h1 = bfr(v1), h2 = bfr(v2), h3 = bfr(v3);
  unsigned w0, w1;
  if (lane < 32) {
    w0 = h0 | (h1 << 16);
    w1 = h2 | (h3 << 16);
  } else {
    unsigned l0 = bfr(v0 - asf(h0 << 16)), l1 = bfr(v1 - asf(h1 << 16));
    unsigned l2 = bfr(v2 - asf(h2 << 16)), l3 = bfr(v3 - asf(h3 << 16));
    w0 = l0 | (l1 << 16);
    w1 = l2 | (l3 << 16);
  }
  unsigned short* po = Out + (size_t)wid * 256 + (lane & 31) * 4 + (lane >= 32 ? 128 : 0);
  *(uint2*)po = make_uint2(w0, w1);
}

// ---------------- split-bf16 MFMA GEMM, LDS-staged weights ----------------
template <int KD, bool AGG, bool GATH>
__global__ __launch_bounds__(256, 3)
void mgemm(const unsigned short* __restrict__ Ai, const unsigned short* __restrict__ W1,
           const unsigned short* __restrict__ Bi, const unsigned short* __restrict__ W2,
           const float* __restrict__ Gt, const int* __restrict__ Gidx,
           const float* __restrict__ bias, unsigned short* __restrict__ Oi, int n) {
  __shared__ unsigned short wlds[2][2][4096];  // [buf][hi/lo][slice]
  constexpr int KS = KD / 32;
  constexpr int NS = (AGG ? 2 : 1) * KS;
  constexpr int KLO = KD * 128;
  constexpr int ARS = 2 * KD;
  const int t = threadIdx.x, wv = t >> 6, ln = t & 63;
  const int row0 = blockIdx.x * 128 + wv * 32;
  const int lm = ln & 15, kg = ln >> 4;
  int ar0 = row0 + lm, ar1 = row0 + 16 + lm;
  if (ar0 >= n) ar0 = 0;
  if (ar1 >= n) ar1 = 0;
  const size_t a0off = (size_t)ar0 * ARS, a1off = (size_t)ar1 * ARS;

  f32x4 acc[2][8];
#pragma unroll
  for (int i = 0; i < 2; ++i)
#pragma unroll
    for (int j = 0; j < 8; ++j) acc[i][j] = (f32x4){0.f, 0.f, 0.f, 0.f};

  uint4 sA, sB, sC, sD;
  bf16x8 a0h[2], a0l[2], a1h[2], a1l[2];

  auto ldst = [&](int s) {
    const unsigned short* W = (AGG && s >= KS) ? W2 : W1;
    const unsigned short* ph = W + (s & (KS - 1)) * 4096;
    sA = *(const uint4*)(ph + t * 8);
    sB = *(const uint4*)(ph + 2048 + t * 8);
    sC = *(const uint4*)(ph + KLO + t * 8);
    sD = *(const uint4*)(ph + KLO + 2048 + t * 8);
  };
  auto wrst = [&](int buf) {
    *(uint4*)&wlds[buf][0][t * 8] = sA;
    *(uint4*)&wlds[buf][0][2048 + t * 8] = sB;
    *(uint4*)&wlds[buf][1][t * 8] = sC;
    *(uint4*)&wlds[buf][1][2048 + t * 8] = sD;
  };
  auto loadA = [&](int s, int w) {
    const unsigned short* X = (AGG && s >= KS) ? Bi : Ai;
    int kk = (s & (KS - 1)) * 32 + kg * 8;
    a0h[w] = *(const bf16x8*)(X + a0off + kk);
    a0l[w] = *(const bf16x8*)(X + a0off + KD + kk);
    a1h[w] = *(const bf16x8*)(X + a1off + kk);
    a1l[w] = *(const bf16x8*)(X + a1off + KD + kk);
  };

  ldst(0); wrst(0); loadA(0, 0);
  __syncthreads();

#pragma unroll
  for (int s = 0; s < NS; ++s) {
    const int buf = s & 1;
    if (s + 1 < NS) { ldst(s + 1); loadA(s + 1, buf ^ 1); }
#pragma unroll
    for (int nf = 0; nf < 8; ++nf) {
      const int wo = (nf * 16 + lm) * 32 + kg * 8;
      bf16x8 wh = *(const bf16x8*)&wlds[buf][0][wo];
      bf16x8 wl = *(const bf16x8*)&wlds[buf][1][wo];
      acc[0][nf] = __builtin_amdgcn_mfma_f32_16x16x32_bf16(a0h[buf], wh, acc[0][nf], 0, 0, 0);
      acc[0][nf] = __builtin_amdgcn_mfma_f32_16x16x32_bf16(a0h[buf], wl, acc[0][nf], 0, 0, 0);
      acc[0][nf] = __builtin_amdgcn_mfma_f32_16x16x32_bf16(a0l[buf], wh, acc[0][nf], 0, 0, 0);
      acc[1][nf] = __builtin_amdgcn_mfma_f32_16x16x32_bf16(a1h[buf], wh, acc[1][nf], 0, 0, 0);
      acc[1][nf] = __builtin_amdgcn_mfma_f32_16x16x32_bf16(a1h[buf], wl, acc[1][nf], 0, 0, 0);
      acc[1][nf] = __builtin_amdgcn_mfma_f32_16x16x32_bf16(a1l[buf], wh, acc[1][nf], 0, 0, 0);
    }
    if (s + 1 < NS) wrst(buf ^ 1);
    __syncthreads();
  }

  float4 bq0 = *(const float4*)&bias[lm * 8];
  float4 bq1 = *(const float4*)&bias[lm * 8 + 4];
  float bsv[8] = {bq0.x, bq0.y, bq0.z, bq0.w, bq1.x, bq1.y, bq1.z, bq1.w};
#pragma unroll
  for (int mf = 0; mf < 2; ++mf)
#pragma unroll
    for (int rr = 0; rr < 4; ++rr) {
      int row = row0 + mf * 16 + kg * 4 + rr;
      if (row >= n) continue;
      float gvv[8];
      if (GATH) {
        const float* grow = Gt + (size_t)Gidx[row] * H + lm * 8;
        float4 g0 = *(const float4*)grow;
        float4 g1 = *(const float4*)(grow + 4);
        gvv[0] = g0.x; gvv[1] = g0.y; gvv[2] = g0.z; gvv[3] = g0.w;
        gvv[4] = g1.x; gvv[5] = g1.y; gvv[6] = g1.z; gvv[7] = g1.w;
      }
      us8 hv, lv;
#pragma unroll
      for (int nf = 0; nf < 8; ++nf) {
        float v = acc[mf][nf][rr] + bsv[nf];
        if (GATH) v += gvv[nf];
        v = fmaxf(v, 0.f);
        unsigned h = bfr(v);
        hv[nf] = (unsigned short)h;
        lv[nf] = (unsigned short)bfr(v - asf(h << 16));
      }
      *(us8*)(Oi + (size_t)row * 256 + lm * 8) = hv;
      *(us8*)(Oi + (size_t)row * 256 + 128 + lm * 8) = lv;
    }
}

// ---------------- fused small-scale chain (row-resident, fp32) ----------------
// Per block: 32 rows through {D-pass -> outD; n-pass (Wa·cur + Wu·P [+gather] +
// bias, relu); enc0; enc1} entirely in LDS. Thread: r=t>>3, cols (t&7)*4+32g.
template <bool GATH, bool SCALEP>
__global__ __launch_bounds__(256)
void fused_small(const float* __restrict__ cur_g,
                 const float* __restrict__ Wd, const float* __restrict__ Wa,
                 const float* __restrict__ Wu,
                 const float* __restrict__ P, const float* __restrict__ pscale,
                 const float* __restrict__ Gt,
                 const float* __restrict__ bn,
                 const float* __restrict__ We0, const float* __restrict__ be0,
                 const float* __restrict__ We1, const float* __restrict__ be1,
                 float* __restrict__ outD, float* __restrict__ out_g, int n) {
  __shared__ float A[32][132];
  __shared__ float Pt[32][132];
  __shared__ float Nx[32][132];
  __shared__ float Wc[16][132];
  const int t = threadIdx.x;
  const int r = t >> 3;
  const int c = (t & 7) * 4;
  const int row0 = blockIdx.x * 32;
  const int row = row0 + r;
  const bool act = row < n;

  // stage cur & P tiles (coalesced)
  for (int i = t; i < 32 * 32; i += 256) {
    int rr = i >> 5, cc = (i & 31) * 4;
    int grow = row0 + rr;
    float4 v = make_float4(0, 0, 0, 0), pv = make_float4(0, 0, 0, 0);
    if (grow < n) {
      v = *(const float4*)&cur_g[(size_t)grow * H + cc];
      pv = *(const float4*)&P[(size_t)grow * H + cc];
      if (SCALEP) {
        float s = pscale[grow];
        pv.x *= s; pv.y *= s; pv.z *= s; pv.w *= s;
      }
    }
    *(float4*)&A[rr][cc] = v;
    *(float4*)&Pt[rr][cc] = pv;
  }

  float acc[16];
  auto gemmpass = [&](const float (*S)[132], const float* __restrict__ W) {
    for (int kc = 0; kc < 8; ++kc) {
      __syncthreads();
      for (int i = t; i < 16 * 32; i += 256) {
        int kk = i >> 5, cc = (i & 31) * 4;
        *(float4*)&Wc[kk][cc] = *(const float4*)&W[(size_t)(kc * 16 + kk) * H + cc];
      }
      __syncthreads();
#pragma unroll
      for (int kk = 0; kk < 16; ++kk) {
        float a = S[r][kc * 16 + kk];
#pragma unroll
        for (int g = 0; g < 4; ++g) {
          float4 w = *(const float4*)&Wc[kk][g * 32 + c];
          acc[g * 4 + 0] += a * w.x;
          acc[g * 4 + 1] += a * w.y;
          acc[g * 4 + 2] += a * w.z;
          acc[g * 4 + 3] += a * w.w;
        }
      }
    }
  };

  // ---- D pass: outD = cur @ Wd (raw) ----
#pragma unroll
  for (int i = 0; i < 16; ++i) acc[i] = 0.f;
  gemmpass(A, Wd);
  if (act) {
#pragma unroll
    for (int g = 0; g < 4; ++g)
      *(float4*)&outD[(size_t)row * H + g * 32 + c] =
          make_float4(acc[g * 4], acc[g * 4 + 1], acc[g * 4 + 2], acc[g * 4 + 3]);
  }

  // ---- n pass: relu(cur@Wa + P@Wu [+ Gt[row/F]] + bn) -> Nx ----
#pragma unroll
  for (int g = 0; g < 4; ++g) {
    float4 b = *(const float4*)&bn[g * 32 + c];
    acc[g * 4] = b.x; acc[g * 4 + 1] = b.y; acc[g * 4 + 2] = b.z; acc[g * 4 + 3] = b.w;
  }
  gemmpass(A, Wa);
  gemmpass(Pt, Wu);
  if (GATH && act) {
    const float* grow = Gt + (size_t)(row / F) * H;
#pragma unroll
    for (int g = 0; g < 4; ++g) {
      float4 gv = *(const float4*)&grow[g * 32 + c];
      acc[g * 4] += gv.x; acc[g * 4 + 1] += gv.y;
      acc[g * 4 + 2] += gv.z; acc[g * 4 + 3] += gv.w;
    }
  }
#pragma unroll
  for (int g = 0; g < 4; ++g)
    *(float4*)&Nx[r][g * 32 + c] =
        make_float4(fmaxf(acc[g * 4], 0.f), fmaxf(acc[g * 4 + 1], 0.f),
                    fmaxf(acc[g * 4 + 2], 0.f), fmaxf(acc[g * 4 + 3], 0.f));

  // ---- enc layer 0: relu(Nx@We0 + be0) -> A ----
#pragma unroll
  for (int g = 0; g < 4; ++g) {
    float4 b = *(const float4*)&be0[g * 32 + c];
    acc[g * 4] = b.x; acc[g * 4 + 1] = b.y; acc[g * 4 + 2] = b.z; acc[g * 4 + 3] = b.w;
  }
  gemmpass(Nx, We0);
  __syncthreads();
#pragma unroll
  for (int g = 0; g < 4; ++g)
    *(float4*)&A[r][g * 32 + c] =
        make_float4(fmaxf(acc[g * 4], 0.f), fmaxf(acc[g * 4 + 1], 0.f),
                    fmaxf(acc[g * 4 + 2], 0.f), fmaxf(acc[g * 4 + 3], 0.f));

  // ---- enc layer 1: relu(A@We1 + be1) -> out_g ----
#pragma unroll
  for (int g = 0; g < 4; ++g) {
    float4 b = *(const float4*)&be1[g * 32 + c];
    acc[g * 4] = b.x; acc[g * 4 + 1] = b.y; acc[g * 4 + 2] = b.z; acc[g * 4 + 3] = b.w;
  }
  gemmpass(A, We1);
  if (act) {
#pragma unroll
    for (int g = 0; g < 4; ++g)
      *(float4*)&out_g[(size_t)row * H + g * 32 + c] =
          make_float4(fmaxf(acc[g * 4], 0.f), fmaxf(acc[g * 4 + 1], 0.f),
                      fmaxf(acc[g * 4 + 2], 0.f), fmaxf(acc[g * 4 + 3], 0.f));
  }
}

// ---------------- initial h1/h2: enc-plain on zeros => identical rows ----------------
// h = relu(relu(b[0]) @ Ws[1] + b[1]) broadcast to all rows.
__global__ void init_bcast(const float* __restrict__ Ws1, const float* __restrict__ b1,
                           const float* __restrict__ Ws2, const float* __restrict__ b2,
                           float* __restrict__ h1, float* __restrict__ h2) {
  __shared__ float z0[128];
  int t = threadIdx.x;  // 128
  bool ish2 = (blockIdx.x == 20);
  const float* W = ish2 ? Ws2 : Ws1;
  const float* bb = ish2 ? b2 : b1;
  z0[t] = fmaxf(bb[t], 0.f);
  __syncthreads();
  float s = bb[128 + t];
  for (int k = 0; k < 128; ++k) s += z0[k] * W[16384 + k * 128 + t];
  s = fmaxf(s, 0.f);
  if (ish2) {
    for (int r = 0; r < B; ++r) h2[(size_t)r * H + t] = s;
  } else {
    int r0 = blockIdx.x * 100;
    for (int r = 0; r < 100; ++r) h1[(size_t)(r0 + r) * H + t] = s;
  }
}

// ---------------- pooling (interleaved rows) ----------------
__global__ void pool_p01(const unsigned short* __restrict__ Act,
                         const int* __restrict__ a0l, const int* __restrict__ b0,
                         float* __restrict__ p01s) {
  __shared__ float acc[F][H];
  int t = threadIdx.x;  // 128
#pragma unroll
  for (int f = 0; f < F; ++f) acc[f][t] = 0.f;
  int rowbase = blockIdx.x * 250;
  for (int i = 0; i < 250; ++i) {
    size_t r = (size_t)(rowbase + i) * 256 + t;
    acc[a0l[rowbase + i]][t] += asf((unsigned)Act[r] << 16) + asf((unsigned)Act[r + 128] << 16);
  }
  int g = b0[rowbase];
#pragma unroll
  for (int f = 0; f < F; ++f)
    atomicAdd(&p01s[((size_t)(g * F + f)) * H + t], acc[f][t]);
}

__global__ void pool_g0(const unsigned short* __restrict__ Act,
                        const int* __restrict__ b0, float* __restrict__ g0s) {
  int t = threadIdx.x;
  int rowbase = blockIdx.x * 250;
  float a = 0.f;
  for (int i = 0; i < 250; ++i) {
    size_t r = (size_t)(rowbase + i) * 256 + t;
    a += asf((unsigned)Act[r] << 16) + asf((unsigned)Act[r + 128] << 16);
  }
  atomicAdd(&g0s[(size_t)b0[rowbase] * H + t], a);
}

__global__ void mean40(const float* __restrict__ hin, float* __restrict__ outp) {
  int t = threadIdx.x, g = blockIdx.x;
  float a = 0.f;
  for (int i = 0; i < F; ++i) a += hin[(size_t)(g * F + i) * H + t];
  outp[(size_t)g * H + t] = a * (1.0f / F);
}

// ---------------- head MLP ----------------
__global__ void head_k(const float* __restrict__ g0s, const float* __restrict__ rdegB,
                       const float* __restrict__ g1, const float* __restrict__ h2,
                       const float* __restrict__ W1h, const float* __restrict__ b1h,
                       const float* __restrict__ W2h, const float* __restrict__ b2h,
                       float* __restrict__ out) {
  __shared__ float gv[3 * H];
  __shared__ float z[H];
  int b = blockIdx.x, t = threadIdx.x;
  gv[t] = g0s[(size_t)b * H + t] * rdegB[b];
  gv[H + t] = g1[(size_t)b * H + t];
  gv[2 * H + t] = h2[(size_t)b * H + t];
  __syncthreads();
  float s = b1h[t];
  for (int k = 0; k < 3 * H; ++k) s += gv[k] * W1h[k * H + t];
  z[t] = fmaxf(s, 0.f);
  __syncthreads();
  if (t < C) {
    float o = b2h[t];
    for (int k = 0; k < H; ++k) o += z[k] * W2h[k * C + t];
    out[b * C + t] = o;
  }
}

}  // namespace

extern "C" void kernel_launch(void* const* d_in, const int* in_sizes, int n_in,
                              void* d_out, int out_size, void* d_ws, size_t ws_size,
                              hipStream_t stream) {
  (void)in_sizes; (void)n_in; (void)out_size; (void)ws_size;
  const float* x0   = (const float*)d_in[0];
  const int*   ei   = (const int*)d_in[1];
  const int*   src  = ei;
  const int*   dst  = ei + E;
  const int*   b0   = (const int*)d_in[2];
  const int*   a0l  = (const int*)d_in[3];
  const float* Wp   = (const float*)d_in[4];
  const float* bp   = (const float*)d_in[5];
  const float* e0in_Ws = (const float*)d_in[6];
  const float* e0in_Wn = (const float*)d_in[7];
  const float* e0in_b  = (const float*)d_in[8];
  const float* enc0_Ws = (const float*)d_in[9];
  const float* enc0_Wn = (const float*)d_in[10];
  const float* enc0_b  = (const float*)d_in[11];
  const float* e1in_Ws = (const float*)d_in[12];
  const float* e1in_b  = (const float*)d_in[13];
  const float* e2in_Ws = (const float*)d_in[14];
  const float* e2in_b  = (const float*)d_in[15];
  const float* enc1_Ws = (const float*)d_in[16];
  const float* enc1_b  = (const float*)d_in[17];
  const float* enc2_Ws = (const float*)d_in[18];
  const float* enc2_b  = (const float*)d_in[19];
  const float* A0 = (const float*)d_in[20];
  const float* A1 = (const float*)d_in[21];
  const float* A2 = (const float*)d_in[22];
  const float* U0 = (const float*)d_in[23];
  const float* U1 = (const float*)d_in[24];
  const float* D1 = (const float*)d_in[25];
  const float* D2 = (const float*)d_in[26];
  const float* ib0 = (const float*)d_in[27];
  const float* ib1 = (const float*)d_in[28];
  const float* ib2 = (const float*)d_in[29];
  const float* H1w = (const float*)d_in[30];
  const float* hb1 = (const float*)d_in[31];
  const float* H2w = (const float*)d_in[32];
  const float* hb2 = (const float*)d_in[33];
  float* out = (float*)d_out;

  // ---- workspace carve ----
  char* p = (char*)d_ws;
  auto carve = [&](size_t bytes) {
    char* r = p;
    p += (bytes + 255) & ~(size_t)255;
    return r;
  };
  char* z0 = p;  // zeroed-every-call region
  int*   deg    = (int*)carve((size_t)N * 4);
  int*   cursor = (int*)carve((size_t)N * 4);
  int*   cnt1   = (int*)carve((size_t)TF * 4);
  float* g0s    = (float*)carve((size_t)B * H * 4);
  size_t zbytes = (size_t)(p - z0);
  unsigned short* h0i  = (unsigned short*)carve((size_t)N * 256 * 2);
  unsigned short* aggi = (unsigned short*)carve((size_t)N * 256 * 2);
  float* h1a  = (float*)carve((size_t)TF * H * 4);
  float* h2a  = (float*)carve((size_t)B * H * 4);
  float* h1d  = (float*)carve((size_t)TF * H * 4);
  float* h2d  = (float*)carve((size_t)B * H * 4);
  float* p01s = (float*)carve((size_t)TF * H * 4);
  float* p12  = (float*)carve((size_t)B * H * 4);
  float* g1   = (float*)carve((size_t)B * H * 4);
  float* rdeg = (float*)carve((size_t)N * 4);
  float* rdeg1 = (float*)carve((size_t)TF * 4);
  float* rdegB = (float*)carve(64 * 4);
  int* offs    = (int*)carve((size_t)(N + 64) * 4);
  int* srcS    = (int*)carve((size_t)E * 4);
  int* part    = (int*)carve(128 * 4);
  int* partEx  = (int*)carve(128 * 4);
  int* assign0 = (int*)carve((size_t)N * 4);
  int* assign1 = (int*)carve((size_t)TF * 4);
  unsigned short* wt  = (unsigned short*)carve((size_t)9 * 32768 * 2);
  unsigned short* wt9 = (unsigned short*)carve((size_t)16384 * 2);
  unsigned short* xs  = aggi;  // alias: x0-split used only before first agg_k

  const int HH = H * H;
  const int MG = (N + 127) / 128;  // 782

  // ---- CSR + histograms + weight/x0 split ----
  hipMemsetAsync(z0, 0, zbytes, stream);
  hist_edges<<<(E + 255) / 256, 256, 0, stream>>>(dst, deg);
  hist_nodes<<<(N + 255) / 256, 256, 0, stream>>>(b0, a0l, cnt1, assign0);
  const int nb1 = (N + 1023) / 1024;
  scan1<<<nb1, 256, 0, stream>>>(deg, offs, part);
  scan2<<<1, 128, 0, stream>>>(part, partEx, nb1);
  scan3<<<(N + 255) / 256, 256, 0, stream>>>(offs, partEx, deg, rdeg, cnt1, rdeg1,
                                             rdegB, assign1);
  scatter_k<<<(E + 255) / 256, 256, 0, stream>>>(src, dst, offs, cursor, srcS);
  {
    WPtrs wp;
    wp.w[0] = e0in_Ws;      wp.w[1] = e0in_Ws + HH;
    wp.w[2] = e0in_Wn;      wp.w[3] = e0in_Wn + HH;
    wp.w[4] = enc0_Ws;      wp.w[5] = enc0_Ws + HH;
    wp.w[6] = enc0_Wn;      wp.w[7] = enc0_Wn + HH;
    wp.w[8] = A0;
    conv_w<<<9 * 64, 256, 0, stream>>>(wp, wt);
  }
  conv_wp<<<32, 256, 0, stream>>>(Wp, wt9);
  x0split<<<(N * D0 + 255) / 256, 256, 0, stream>>>(x0, xs);

  // ---- input projection (MFMA, K=64) ----
  mgemm<64, false, false><<<MG, 256, 0, stream>>>(
      xs, wt9, nullptr, nullptr, nullptr, nullptr, bp, h0i, N);

  auto encEdgeM = [&](int wsIdx, int wnIdx, const float* barr) {
    for (int l = 0; l < 2; ++l) {
      agg_k<<<N / 4, 256, 0, stream>>>(h0i, offs, srcS, rdeg, aggi);
      mgemm<128, true, false><<<MG, 256, 0, stream>>>(
          h0i, wt + (size_t)(wsIdx + l) * 32768, aggi,
          wt + (size_t)(wnIdx + l) * 32768, nullptr, nullptr, barr + l * H, h0i, N);
    }
  };

  encEdgeM(0, 2, e0in_b);
  init_bcast<<<21, 128, 0, stream>>>(e1in_Ws, e1in_b, e2in_Ws, e2in_b, h1a, h2a);

  for (int step = 0; step < 2; ++step) {
    hipMemsetAsync(p01s, 0, (size_t)TF * H * 4, stream);
    pool_p01<<<400, 128, 0, stream>>>(h0i, a0l, b0, p01s);
    mean40<<<B, 128, 0, stream>>>(h1a, p12);
    // h2 chain: D2 -> h2d; n2 = relu(h2@A2 + p12@U1 + ib2); enc2 x2 (in-place)
    fused_small<false, false><<<(B + 31) / 32, 256, 0, stream>>>(
        h2a, D2, A2, U1, p12, nullptr, nullptr, ib2,
        enc2_Ws, enc2_b, enc2_Ws + HH, enc2_b + H, h2d, h2a, B);
    // h1 chain: D1 -> h1d; n1 = relu(h1@A1 + (p01s*rdeg1)@U0 + h2d[row/F] + ib1); enc1 x2
    fused_small<true, true><<<(TF + 31) / 32, 256, 0, stream>>>(
        h1a, D1, A1, U0, p01s, rdeg1, h2d, ib1,
        enc1_Ws, enc1_b, enc1_Ws + HH, enc1_b + H, h1d, h1a, TF);
    // n0 = relu(h0@A0 + h1d[assign0] + ib0)   (in-place, MFMA)
    mgemm<128, false, true><<<MG, 256, 0, stream>>>(
        h0i, wt + (size_t)8 * 32768, nullptr, nullptr, h1d, assign0, ib0, h0i, N);
    encEdgeM(4, 6, enc0_b);
  }

  pool_g0<<<400, 128, 0, stream>>>(h0i, b0, g0s);
  mean40<<<B, 128, 0, stream>>>(h1a, g1);
  head_k<<<B, 128, 0, stream>>>(g0s, rdegB, g1, h2a, H1w, hb1, H2w, hb2, out);
}